// Round 1
// baseline (918.742 us; speedup 1.0000x reference)
//
#include <hip/hip_runtime.h>
#include <cstddef>
#include <cstdint>

// ---------------- CSR construction ----------------

__global__ void count_edges_k(const int* __restrict__ ei, int* __restrict__ counts,
                              int E, int N) {
    int e = blockIdx.x * blockDim.x + threadIdx.x;
    int tot = E + N;
    if (e >= tot) return;
    int d = (e < E) ? ei[E + e] : (e - E);
    atomicAdd(&counts[d], 1);
}

__global__ __launch_bounds__(1024) void scan_k(const int* __restrict__ counts,
                                               int* __restrict__ offs,
                                               int* __restrict__ cursor, int N) {
    __shared__ int wsum[16];
    __shared__ int carry_s;
    int tid = threadIdx.x, lane = tid & 63, w = tid >> 6;
    if (tid == 0) { carry_s = 0; offs[0] = 0; }
    __syncthreads();
    for (int base = 0; base < N; base += 1024) {
        int i = base + tid;
        int v = (i < N) ? counts[i] : 0;
        int x = v;
        #pragma unroll
        for (int d = 1; d < 64; d <<= 1) {
            int t = __shfl_up(x, d, 64);
            if (lane >= d) x += t;
        }
        if (lane == 63) wsum[w] = x;
        __syncthreads();
        if (tid == 0) {
            int run = 0;
            for (int k = 0; k < 16; k++) { run += wsum[k]; wsum[k] = run; }
        }
        __syncthreads();
        int incl = x + (w > 0 ? wsum[w - 1] : 0) + carry_s;
        if (i < N) { offs[i + 1] = incl; cursor[i] = incl - v; }
        __syncthreads();
        if (tid == 0) carry_s += wsum[15];
        __syncthreads();
    }
}

__global__ void fill_csr_k(const int* __restrict__ ei, int* __restrict__ cursor,
                           int* __restrict__ csr_src, int E, int N) {
    int e = blockIdx.x * blockDim.x + threadIdx.x;
    int tot = E + N;
    if (e >= tot) return;
    int s, d;
    if (e < E) { s = ei[e]; d = ei[E + e]; }
    else       { s = e - E; d = s; }
    int pos = atomicAdd(&cursor[d], 1);
    csr_src[pos] = s;
}

// ---------------- f32 tiled GEMM: C = A[M,K] @ B[K,Nc] (+bias) (+relu) ----------------
// 64x64 tile, BK=16, 256 threads, 4x4 per thread.

__global__ __launch_bounds__(256) void gemm_k(const float* __restrict__ A,
                                              const float* __restrict__ B,
                                              const float* __restrict__ bias,
                                              float* __restrict__ C,
                                              int M, int K, int Nc, int relu) {
    const int BK = 16;
    __shared__ float As[BK][68];  // [k][m], pad keeps 16B alignment
    __shared__ float Bs[BK][68];  // [k][n]
    int bm = blockIdx.x * 64, bn = blockIdx.y * 64;
    int tid = threadIdx.x;
    int tm = (tid / 16) * 4, tn = (tid % 16) * 4;
    float acc[4][4] = {};
    for (int k0 = 0; k0 < K; k0 += BK) {
        for (int i = tid; i < 64 * BK; i += 256) {
            int m = i / BK, k = i % BK;
            As[k][m] = (bm + m < M) ? A[(size_t)(bm + m) * K + k0 + k] : 0.f;
        }
        for (int i = tid; i < BK * 64; i += 256) {
            int k = i / 64, n = i % 64;
            Bs[k][n] = B[(size_t)(k0 + k) * Nc + bn + n];
        }
        __syncthreads();
        #pragma unroll
        for (int k = 0; k < BK; k++) {
            float a[4], b[4];
            #pragma unroll
            for (int i = 0; i < 4; i++) a[i] = As[k][tm + i];
            #pragma unroll
            for (int j = 0; j < 4; j++) b[j] = Bs[k][tn + j];
            #pragma unroll
            for (int i = 0; i < 4; i++)
                #pragma unroll
                for (int j = 0; j < 4; j++) acc[i][j] += a[i] * b[j];
        }
        __syncthreads();
    }
    #pragma unroll
    for (int i = 0; i < 4; i++) {
        int m = bm + tm + i;
        if (m >= M) continue;
        #pragma unroll
        for (int j = 0; j < 4; j++) {
            int n = bn + tn + j;
            float v = acc[i][j] + (bias ? bias[n] : 0.f);
            if (relu) v = fmaxf(v, 0.f);
            C[(size_t)m * Nc + n] = v;
        }
    }
}

// ---------------- per-node attention logits: al_s[n,h]=dot(h[n,h,:],att_s[h,:]) ----------------
// blockDim = H*C (C must be 64 so each head occupies one wave)

__global__ void att_k(const float* __restrict__ h, const float* __restrict__ as_,
                      const float* __restrict__ ad_, float* __restrict__ al_s,
                      float* __restrict__ al_d, int H, int C) {
    int n = blockIdx.x;
    int t = threadIdx.x;
    int hd = t / C;
    int c = t % C;
    float hv = h[(size_t)n * H * C + t];
    float ps = hv * as_[t];
    float pd = hv * ad_[t];
    #pragma unroll
    for (int d = 32; d > 0; d >>= 1) {
        ps += __shfl_down(ps, d, 64);
        pd += __shfl_down(pd, d, 64);
    }
    if (c == 0) {
        al_s[(size_t)n * H + hd] = ps;
        al_d[(size_t)n * H + hd] = pd;
    }
}

// ---------------- GAT aggregation: one block (C*H threads) per dst node ----------------

template<int C, int H>
__global__ void gat_agg_k(const float* __restrict__ h, const float* __restrict__ al_s,
                          const float* __restrict__ al_d, const int* __restrict__ offs,
                          const int* __restrict__ csr_src, const float* __restrict__ bias,
                          float* __restrict__ out, int relu) {
    int n = blockIdx.x;
    int t = threadIdx.x;          // channel within concat output
    int hd = t / C;
    int beg = offs[n], end = offs[n + 1];
    float ald = al_d[(size_t)n * H + hd];
    // pass 1: segment max (redundant across threads in a head group; al_s is cached)
    float m = -1e30f;
    for (int e = beg; e < end; e++) {
        int s = csr_src[e];
        float l = al_s[s * H + hd] + ald;
        l = (l > 0.f) ? l : 0.2f * l;
        m = fmaxf(m, l);
    }
    // pass 2: sum of exp
    float z = 0.f;
    for (int e = beg; e < end; e++) {
        int s = csr_src[e];
        float l = al_s[s * H + hd] + ald;
        l = (l > 0.f) ? l : 0.2f * l;
        z += __expf(l - m);
    }
    float rz = 1.f / z;
    // pass 3: weighted gather of h rows (coalesced: block reads C*H contiguous floats)
    float acc = 0.f;
    for (int e = beg; e < end; e++) {
        int s = csr_src[e];
        float l = al_s[s * H + hd] + ald;
        l = (l > 0.f) ? l : 0.2f * l;
        float a = __expf(l - m) * rz;
        acc += a * h[(size_t)s * (C * H) + t];
    }
    float v = acc + bias[t];
    if (relu) v = fmaxf(v, 0.f);
    out[(size_t)n * (C * H) + t] = v;
}

// ---------------- launch ----------------

extern "C" void kernel_launch(void* const* d_in, const int* in_sizes, int n_in,
                              void* d_out, int out_size, void* d_ws, size_t ws_size,
                              hipStream_t stream) {
    const float* x   = (const float*)d_in[0];
    const int*   ei  = (const int*)d_in[1];
    const float* W1  = (const float*)d_in[2];
    const float* as1 = (const float*)d_in[3];
    const float* ad1 = (const float*)d_in[4];
    const float* b1  = (const float*)d_in[5];
    const float* W2  = (const float*)d_in[6];
    const float* as2 = (const float*)d_in[7];
    const float* ad2 = (const float*)d_in[8];
    const float* b2  = (const float*)d_in[9];
    const float* Wf  = (const float*)d_in[10];
    const float* bf  = (const float*)d_in[11];
    float* out = (float*)d_out;

    int N = in_sizes[0] / 256;   // 50000
    int E = in_sizes[1] / 2;     // 800000
    int ET = E + N;

    char* w = (char*)d_ws;
    float* h1   = (float*)w;                                  // N*256 f32
    float* out1 = (float*)(w + (size_t)N * 256 * 4);          // N*256 f32
    char*  p    = w + (size_t)N * 256 * 4 * 2;
    float* al_s1 = (float*)p;            p += (size_t)N * 4 * 4;
    float* al_d1 = (float*)p;            p += (size_t)N * 4 * 4;
    float* al_s2 = (float*)p;            p += (size_t)N * 4;
    float* al_d2 = (float*)p;            p += (size_t)N * 4;
    int* counts  = (int*)p;              p += (size_t)N * 4;
    int* offs    = (int*)p;              p += (size_t)(N + 1) * 4;
    int* cursor  = (int*)p;              p += (size_t)N * 4;
    int* csr_src = (int*)p;              p += (size_t)ET * 4;
    // layer-2 buffers reuse the (dead) h1 region
    float* h2   = h1;                    // N*64
    float* out2 = h1 + (size_t)N * 64;   // N*64

    // CSR build
    hipMemsetAsync(counts, 0, (size_t)N * sizeof(int), stream);
    count_edges_k<<<(ET + 255) / 256, 256, 0, stream>>>(ei, counts, E, N);
    scan_k<<<1, 1024, 0, stream>>>(counts, offs, cursor, N);
    fill_csr_k<<<(ET + 255) / 256, 256, 0, stream>>>(ei, cursor, csr_src, E, N);

    // layer 1: h1 = x @ W1
    dim3 g1((N + 63) / 64, 256 / 64);
    gemm_k<<<g1, 256, 0, stream>>>(x, W1, nullptr, h1, N, 256, 256, 0);
    att_k<<<N, 256, 0, stream>>>(h1, as1, ad1, al_s1, al_d1, 4, 64);
    gat_agg_k<64, 4><<<N, 256, 0, stream>>>(h1, al_s1, al_d1, offs, csr_src, b1, out1, 1);

    // layer 2: h2 = out1 @ W2
    dim3 g2((N + 63) / 64, 1);
    gemm_k<<<g2, 256, 0, stream>>>(out1, W2, nullptr, h2, N, 256, 64, 0);
    att_k<<<N, 64, 0, stream>>>(h2, as2, ad2, al_s2, al_d2, 1, 64);
    gat_agg_k<64, 1><<<N, 64, 0, stream>>>(h2, al_s2, al_d2, offs, csr_src, b2, out2, 0);

    // final: out = out2 @ Wf + bf
    dim3 g3((N + 63) / 64, 256 / 64);
    gemm_k<<<g3, 256, 0, stream>>>(out2, Wf, bf, out, N, 64, 256, 0);
}

// Round 2
// 565.466 us; speedup vs baseline: 1.6248x; 1.6248x over previous
//
#include <hip/hip_runtime.h>
#include <cstddef>
#include <cstdint>

// ---------------- CSR construction ----------------

__global__ void count_edges_k(const int* __restrict__ ei, int* __restrict__ counts,
                              int E, int N) {
    int e = blockIdx.x * blockDim.x + threadIdx.x;
    int tot = E + N;
    if (e >= tot) return;
    int d = (e < E) ? ei[E + e] : (e - E);
    atomicAdd(&counts[d], 1);
}

__global__ __launch_bounds__(1024) void scan_k(const int* __restrict__ counts,
                                               int* __restrict__ offs,
                                               int* __restrict__ cursor, int N) {
    __shared__ int wsum[16];
    __shared__ int carry_s;
    int tid = threadIdx.x, lane = tid & 63, w = tid >> 6;
    if (tid == 0) { carry_s = 0; offs[0] = 0; }
    __syncthreads();
    for (int base = 0; base < N; base += 1024) {
        int i = base + tid;
        int v = (i < N) ? counts[i] : 0;
        int x = v;
        #pragma unroll
        for (int d = 1; d < 64; d <<= 1) {
            int t = __shfl_up(x, d, 64);
            if (lane >= d) x += t;
        }
        if (lane == 63) wsum[w] = x;
        __syncthreads();
        if (tid == 0) {
            int run = 0;
            for (int k = 0; k < 16; k++) { run += wsum[k]; wsum[k] = run; }
        }
        __syncthreads();
        int incl = x + (w > 0 ? wsum[w - 1] : 0) + carry_s;
        if (i < N) { offs[i + 1] = incl; cursor[i] = incl - v; }
        __syncthreads();
        if (tid == 0) carry_s += wsum[15];
        __syncthreads();
    }
}

__global__ void fill_csr_k(const int* __restrict__ ei, int* __restrict__ cursor,
                           int* __restrict__ csr_src, int E, int N) {
    int e = blockIdx.x * blockDim.x + threadIdx.x;
    int tot = E + N;
    if (e >= tot) return;
    int s, d;
    if (e < E) { s = ei[e]; d = ei[E + e]; }
    else       { s = e - E; d = s; }
    int pos = atomicAdd(&cursor[d], 1);
    csr_src[pos] = s;
}

// ---------------- f32 tiled GEMM: C = A[M,K] @ B[K,Nc] (+bias) (+relu) ----------------

__global__ __launch_bounds__(256) void gemm_k(const float* __restrict__ A,
                                              const float* __restrict__ B,
                                              const float* __restrict__ bias,
                                              float* __restrict__ C,
                                              int M, int K, int Nc, int relu) {
    const int BK = 16;
    __shared__ float As[BK][68];
    __shared__ float Bs[BK][68];
    int bm = blockIdx.x * 64, bn = blockIdx.y * 64;
    int tid = threadIdx.x;
    int tm = (tid / 16) * 4, tn = (tid % 16) * 4;
    float acc[4][4] = {};
    for (int k0 = 0; k0 < K; k0 += BK) {
        for (int i = tid; i < 64 * BK; i += 256) {
            int m = i / BK, k = i % BK;
            As[k][m] = (bm + m < M) ? A[(size_t)(bm + m) * K + k0 + k] : 0.f;
        }
        for (int i = tid; i < BK * 64; i += 256) {
            int k = i / 64, n = i % 64;
            Bs[k][n] = B[(size_t)(k0 + k) * Nc + bn + n];
        }
        __syncthreads();
        #pragma unroll
        for (int k = 0; k < BK; k++) {
            float a[4], b[4];
            #pragma unroll
            for (int i = 0; i < 4; i++) a[i] = As[k][tm + i];
            #pragma unroll
            for (int j = 0; j < 4; j++) b[j] = Bs[k][tn + j];
            #pragma unroll
            for (int i = 0; i < 4; i++)
                #pragma unroll
                for (int j = 0; j < 4; j++) acc[i][j] += a[i] * b[j];
        }
        __syncthreads();
    }
    #pragma unroll
    for (int i = 0; i < 4; i++) {
        int m = bm + tm + i;
        if (m >= M) continue;
        #pragma unroll
        for (int j = 0; j < 4; j++) {
            int n = bn + tn + j;
            float v = acc[i][j] + (bias ? bias[n] : 0.f);
            if (relu) v = fmaxf(v, 0.f);
            C[(size_t)m * Nc + n] = v;
        }
    }
}

// ---------------- per-node attention logits ----------------

__global__ void att_k(const float* __restrict__ h, const float* __restrict__ as_,
                      const float* __restrict__ ad_, float* __restrict__ al_s,
                      float* __restrict__ al_d, int H, int C) {
    int n = blockIdx.x;
    int t = threadIdx.x;
    int hd = t / C;
    int c = t % C;
    float hv = h[(size_t)n * H * C + t];
    float ps = hv * as_[t];
    float pd = hv * ad_[t];
    #pragma unroll
    for (int d = 32; d > 0; d >>= 1) {
        ps += __shfl_down(ps, d, 64);
        pd += __shfl_down(pd, d, 64);
    }
    if (c == 0) {
        al_s[(size_t)n * H + hd] = ps;
        al_d[(size_t)n * H + hd] = pd;
    }
}

// ---------------- GAT aggregation v2: one wave per (node, head) ----------------
// Edge-parallel online softmax across lanes, then single gather pass.
// C = 64 channels per head; block = 4 waves = 4 (node,head) tasks.

template<int H>
__global__ __launch_bounds__(256) void gat_agg2_k(
    const float* __restrict__ h, const float* __restrict__ al_s,
    const float* __restrict__ al_d, const int* __restrict__ offs,
    const int* __restrict__ csr_src, const float* __restrict__ bias,
    float* __restrict__ out, int NH, int relu)
{
    __shared__ float alds[4][64];
    __shared__ int   slds[4][64];
    const int RS = H * 64;                 // row stride of h / out
    int w = threadIdx.x >> 6, lane = threadIdx.x & 63;
    int g = blockIdx.x * 4 + w;            // (node, head) task id
    if (g >= NH) return;
    int node = g / H, head = g % H;
    int beg = offs[node], end = offs[node + 1];
    float ald = al_d[(size_t)node * H + head];
    float m_run = -1e30f, z_run = 0.f, acc = 0.f;

    for (int base = beg; base < end; base += 64) {
        int cnt = min(64, end - base);
        int s = 0; float l = -1e30f;
        if (lane < cnt) {
            s = csr_src[base + lane];
            float t = al_s[(size_t)s * H + head] + ald;
            l = (t > 0.f) ? t : 0.2f * t;
        }
        // wave max
        float m_c = l;
        #pragma unroll
        for (int d = 32; d; d >>= 1) m_c = fmaxf(m_c, __shfl_xor(m_c, d, 64));
        float m_new = fmaxf(m_run, m_c);
        float p = (lane < cnt) ? __expf(l - m_new) : 0.f;
        // wave sum
        float z_c = p;
        #pragma unroll
        for (int d = 32; d; d >>= 1) z_c += __shfl_xor(z_c, d, 64);
        float scale = __expf(m_run - m_new);   // 0 on first chunk (underflow)
        z_run = z_run * scale + z_c;
        acc *= scale;
        // stash alpha + src for broadcast reads (per-wave LDS slice, in-wave ordering)
        alds[w][lane] = p;
        slds[w][lane] = s;
        #pragma unroll 4
        for (int e = 0; e < cnt; ++e) {
            float a = alds[w][e];
            int ss  = slds[w][e];
            acc += a * h[(size_t)ss * RS + head * 64 + lane];
        }
        m_run = m_new;
    }

    float v = acc / z_run + bias[head * 64 + lane];
    if (relu) v = fmaxf(v, 0.f);
    out[(size_t)node * RS + head * 64 + lane] = v;
}

// ---------------- launch ----------------

extern "C" void kernel_launch(void* const* d_in, const int* in_sizes, int n_in,
                              void* d_out, int out_size, void* d_ws, size_t ws_size,
                              hipStream_t stream) {
    const float* x   = (const float*)d_in[0];
    const int*   ei  = (const int*)d_in[1];
    const float* W1  = (const float*)d_in[2];
    const float* as1 = (const float*)d_in[3];
    const float* ad1 = (const float*)d_in[4];
    const float* b1  = (const float*)d_in[5];
    const float* W2  = (const float*)d_in[6];
    const float* as2 = (const float*)d_in[7];
    const float* ad2 = (const float*)d_in[8];
    const float* b2  = (const float*)d_in[9];
    const float* bf  = (const float*)d_in[11];
    const float* Wf  = (const float*)d_in[10];
    float* out = (float*)d_out;

    int N = in_sizes[0] / 256;   // 50000
    int E = in_sizes[1] / 2;     // 800000
    int ET = E + N;

    char* w = (char*)d_ws;
    float* h1   = (float*)w;                                  // N*256 f32
    float* out1 = (float*)(w + (size_t)N * 256 * 4);          // N*256 f32
    char*  p    = w + (size_t)N * 256 * 4 * 2;
    float* al_s1 = (float*)p;            p += (size_t)N * 4 * 4;
    float* al_d1 = (float*)p;            p += (size_t)N * 4 * 4;
    float* al_s2 = (float*)p;            p += (size_t)N * 4;
    float* al_d2 = (float*)p;            p += (size_t)N * 4;
    int* counts  = (int*)p;              p += (size_t)N * 4;
    int* offs    = (int*)p;              p += (size_t)(N + 1) * 4;
    int* cursor  = (int*)p;              p += (size_t)N * 4;
    int* csr_src = (int*)p;              p += (size_t)ET * 4;
    float* h2   = h1;                    // N*64 (reuses dead h1)
    float* out2 = h1 + (size_t)N * 64;   // N*64

    // CSR build
    hipMemsetAsync(counts, 0, (size_t)N * sizeof(int), stream);
    count_edges_k<<<(ET + 255) / 256, 256, 0, stream>>>(ei, counts, E, N);
    scan_k<<<1, 1024, 0, stream>>>(counts, offs, cursor, N);
    fill_csr_k<<<(ET + 255) / 256, 256, 0, stream>>>(ei, cursor, csr_src, E, N);

    // layer 1
    dim3 g1((N + 63) / 64, 256 / 64);
    gemm_k<<<g1, 256, 0, stream>>>(x, W1, nullptr, h1, N, 256, 256, 0);
    att_k<<<N, 256, 0, stream>>>(h1, as1, ad1, al_s1, al_d1, 4, 64);
    {
        int NH = N * 4;
        gat_agg2_k<4><<<(NH + 3) / 4, 256, 0, stream>>>(h1, al_s1, al_d1, offs, csr_src, b1, out1, NH, 1);
    }

    // layer 2
    dim3 g2((N + 63) / 64, 1);
    gemm_k<<<g2, 256, 0, stream>>>(out1, W2, nullptr, h2, N, 256, 64, 0);
    att_k<<<N, 64, 0, stream>>>(h2, as2, ad2, al_s2, al_d2, 1, 64);
    {
        int NH = N;
        gat_agg2_k<1><<<(NH + 3) / 4, 256, 0, stream>>>(h2, al_s2, al_d2, offs, csr_src, b2, out2, NH, 0);
    }

    // final linear
    dim3 g3((N + 63) / 64, 256 / 64);
    gemm_k<<<g3, 256, 0, stream>>>(out2, Wf, bf, out, N, 64, 256, 0);
}

// Round 3
// 532.796 us; speedup vs baseline: 1.7244x; 1.0613x over previous
//
#include <hip/hip_runtime.h>
#include <cstddef>
#include <cstdint>

// ---------------- CSR construction ----------------

__global__ void count_edges_k(const int* __restrict__ ei, int* __restrict__ counts,
                              int E, int N) {
    int e = blockIdx.x * blockDim.x + threadIdx.x;
    int tot = E + N;
    if (e >= tot) return;
    int d = (e < E) ? ei[E + e] : (e - E);
    atomicAdd(&counts[d], 1);
}

__global__ __launch_bounds__(1024) void scan_k(const int* __restrict__ counts,
                                               int* __restrict__ offs,
                                               int* __restrict__ cursor, int N) {
    __shared__ int wsum[16];
    __shared__ int carry_s;
    int tid = threadIdx.x, lane = tid & 63, w = tid >> 6;
    if (tid == 0) { carry_s = 0; offs[0] = 0; }
    __syncthreads();
    for (int base = 0; base < N; base += 1024) {
        int i = base + tid;
        int v = (i < N) ? counts[i] : 0;
        int x = v;
        #pragma unroll
        for (int d = 1; d < 64; d <<= 1) {
            int t = __shfl_up(x, d, 64);
            if (lane >= d) x += t;
        }
        if (lane == 63) wsum[w] = x;
        __syncthreads();
        if (tid == 0) {
            int run = 0;
            for (int k = 0; k < 16; k++) { run += wsum[k]; wsum[k] = run; }
        }
        __syncthreads();
        int incl = x + (w > 0 ? wsum[w - 1] : 0) + carry_s;
        if (i < N) { offs[i + 1] = incl; cursor[i] = incl - v; }
        __syncthreads();
        if (tid == 0) carry_s += wsum[15];
        __syncthreads();
    }
}

__global__ void fill_csr_k(const int* __restrict__ ei, int* __restrict__ cursor,
                           int* __restrict__ csr_src, int E, int N) {
    int e = blockIdx.x * blockDim.x + threadIdx.x;
    int tot = E + N;
    if (e >= tot) return;
    int s, d;
    if (e < E) { s = ei[e]; d = ei[E + e]; }
    else       { s = e - E; d = s; }
    int pos = atomicAdd(&cursor[d], 1);
    csr_src[pos] = s;
}

// ---------------- f32 tiled GEMM v2: C = A[M,K] @ B[K,Nc] (+bias) (+relu) ----------------
// BM x BN tile, BK=16, 256 threads, TM x TN per thread (8x8 or 8x4).
// Split-half fragment layout keeps ds_read_b128 conflicts <= 2-way (free).
// Row stride +4 floats: 132*4=528B = 33*16B keeps 16B alignment for b128 ops.

template<int BM, int BN, int TM, int TN>
__global__ __launch_bounds__(256) void gemm2_k(const float* __restrict__ A,
                                               const float* __restrict__ B,
                                               const float* __restrict__ bias,
                                               float* __restrict__ C,
                                               int M, int K, int Nc, int relu) {
    const int BK = 16;
    const int RM = TM / 4;            // row chunks (float4s) per thread
    const int RN = TN / 4;            // col chunks per thread
    const int TX = BN / TN;           // threads along n
    __shared__ float As[BK][BM + 4];  // [k][m]
    __shared__ float Bs[BK][BN + 4];  // [k][n]

    int bm = blockIdx.x * BM, bn = blockIdx.y * BN;
    int tid = threadIdx.x;
    int tmg = tid / TX;               // 0..BM/TM-1
    int tng = tid % TX;               // 0..TX-1

    float acc[TM][TN] = {};

    for (int k0 = 0; k0 < K; k0 += BK) {
        // stage A (transpose to [k][m]); scatter writes land ~2-way per bank
        const int AF4 = BM * BK / 4;
        #pragma unroll
        for (int q0 = 0; q0 < AF4; q0 += 256) {
            int q = q0 + tid;
            int m = q / (BK / 4);
            int kq = q % (BK / 4);
            float4 v = make_float4(0.f, 0.f, 0.f, 0.f);
            if (bm + m < M) v = *(const float4*)&A[(size_t)(bm + m) * K + k0 + kq * 4];
            As[kq * 4 + 0][m] = v.x;
            As[kq * 4 + 1][m] = v.y;
            As[kq * 4 + 2][m] = v.z;
            As[kq * 4 + 3][m] = v.w;
        }
        // stage B (contiguous float4 writes)
        const int BF4 = BK * BN / 4;
        #pragma unroll
        for (int q0 = 0; q0 < BF4; q0 += 256) {
            int q = q0 + tid;
            int k = q / (BN / 4);
            int c4 = q % (BN / 4);
            *(float4*)&Bs[k][c4 * 4] = *(const float4*)&B[(size_t)(k0 + k) * Nc + bn + c4 * 4];
        }
        __syncthreads();

        #pragma unroll
        for (int k = 0; k < BK; ++k) {
            float a[TM], b[TN];
            #pragma unroll
            for (int r = 0; r < RM; ++r) {
                float4 v = *(const float4*)&As[k][r * (BM / RM) + tmg * 4];
                a[r * 4 + 0] = v.x; a[r * 4 + 1] = v.y;
                a[r * 4 + 2] = v.z; a[r * 4 + 3] = v.w;
            }
            #pragma unroll
            for (int s = 0; s < RN; ++s) {
                float4 v = *(const float4*)&Bs[k][s * (BN / RN) + tng * 4];
                b[s * 4 + 0] = v.x; b[s * 4 + 1] = v.y;
                b[s * 4 + 2] = v.z; b[s * 4 + 3] = v.w;
            }
            #pragma unroll
            for (int i = 0; i < TM; ++i)
                #pragma unroll
                for (int j = 0; j < TN; ++j)
                    acc[i][j] += a[i] * b[j];
        }
        __syncthreads();
    }

    #pragma unroll
    for (int r = 0; r < RM; ++r) {
        #pragma unroll
        for (int i = 0; i < 4; ++i) {
            int m = bm + r * (BM / RM) + tmg * 4 + i;
            if (m >= M) continue;
            #pragma unroll
            for (int s = 0; s < RN; ++s) {
                int n = bn + s * (BN / RN) + tng * 4;
                float4 v;
                v.x = acc[r * 4 + i][s * 4 + 0] + (bias ? bias[n + 0] : 0.f);
                v.y = acc[r * 4 + i][s * 4 + 1] + (bias ? bias[n + 1] : 0.f);
                v.z = acc[r * 4 + i][s * 4 + 2] + (bias ? bias[n + 2] : 0.f);
                v.w = acc[r * 4 + i][s * 4 + 3] + (bias ? bias[n + 3] : 0.f);
                if (relu) {
                    v.x = fmaxf(v.x, 0.f); v.y = fmaxf(v.y, 0.f);
                    v.z = fmaxf(v.z, 0.f); v.w = fmaxf(v.w, 0.f);
                }
                *(float4*)&C[(size_t)m * Nc + n] = v;
            }
        }
    }
}

// ---------------- per-node attention logits ----------------

__global__ void att_k(const float* __restrict__ h, const float* __restrict__ as_,
                      const float* __restrict__ ad_, float* __restrict__ al_s,
                      float* __restrict__ al_d, int H, int C) {
    int n = blockIdx.x;
    int t = threadIdx.x;
    int hd = t / C;
    int c = t % C;
    float hv = h[(size_t)n * H * C + t];
    float ps = hv * as_[t];
    float pd = hv * ad_[t];
    #pragma unroll
    for (int d = 32; d > 0; d >>= 1) {
        ps += __shfl_down(ps, d, 64);
        pd += __shfl_down(pd, d, 64);
    }
    if (c == 0) {
        al_s[(size_t)n * H + hd] = ps;
        al_d[(size_t)n * H + hd] = pd;
    }
}

// ---------------- GAT aggregation: one wave per (node, head) ----------------

template<int H>
__global__ __launch_bounds__(256) void gat_agg2_k(
    const float* __restrict__ h, const float* __restrict__ al_s,
    const float* __restrict__ al_d, const int* __restrict__ offs,
    const int* __restrict__ csr_src, const float* __restrict__ bias,
    float* __restrict__ out, int NH, int relu)
{
    __shared__ float alds[4][64];
    __shared__ int   slds[4][64];
    const int RS = H * 64;
    int w = threadIdx.x >> 6, lane = threadIdx.x & 63;
    int g = blockIdx.x * 4 + w;
    if (g >= NH) return;
    int node = g / H, head = g % H;
    int beg = offs[node], end = offs[node + 1];
    float ald = al_d[(size_t)node * H + head];
    float m_run = -1e30f, z_run = 0.f, acc = 0.f;

    for (int base = beg; base < end; base += 64) {
        int cnt = min(64, end - base);
        int s = 0; float l = -1e30f;
        if (lane < cnt) {
            s = csr_src[base + lane];
            float t = al_s[(size_t)s * H + head] + ald;
            l = (t > 0.f) ? t : 0.2f * t;
        }
        float m_c = l;
        #pragma unroll
        for (int d = 32; d; d >>= 1) m_c = fmaxf(m_c, __shfl_xor(m_c, d, 64));
        float m_new = fmaxf(m_run, m_c);
        float p = (lane < cnt) ? __expf(l - m_new) : 0.f;
        float z_c = p;
        #pragma unroll
        for (int d = 32; d; d >>= 1) z_c += __shfl_xor(z_c, d, 64);
        float scale = __expf(m_run - m_new);
        z_run = z_run * scale + z_c;
        acc *= scale;
        alds[w][lane] = p;
        slds[w][lane] = s;
        #pragma unroll 4
        for (int e = 0; e < cnt; ++e) {
            float a = alds[w][e];
            int ss  = slds[w][e];
            acc += a * h[(size_t)ss * RS + head * 64 + lane];
        }
        m_run = m_new;
    }

    float v = acc / z_run + bias[head * 64 + lane];
    if (relu) v = fmaxf(v, 0.f);
    out[(size_t)node * RS + head * 64 + lane] = v;
}

// ---------------- launch ----------------

extern "C" void kernel_launch(void* const* d_in, const int* in_sizes, int n_in,
                              void* d_out, int out_size, void* d_ws, size_t ws_size,
                              hipStream_t stream) {
    const float* x   = (const float*)d_in[0];
    const int*   ei  = (const int*)d_in[1];
    const float* W1  = (const float*)d_in[2];
    const float* as1 = (const float*)d_in[3];
    const float* ad1 = (const float*)d_in[4];
    const float* b1  = (const float*)d_in[5];
    const float* W2  = (const float*)d_in[6];
    const float* as2 = (const float*)d_in[7];
    const float* ad2 = (const float*)d_in[8];
    const float* b2  = (const float*)d_in[9];
    const float* Wf  = (const float*)d_in[10];
    const float* bf  = (const float*)d_in[11];
    float* out = (float*)d_out;

    int N = in_sizes[0] / 256;   // 50000
    int E = in_sizes[1] / 2;     // 800000
    int ET = E + N;

    char* w = (char*)d_ws;
    float* h1   = (float*)w;                                  // N*256 f32
    float* out1 = (float*)(w + (size_t)N * 256 * 4);          // N*256 f32
    char*  p    = w + (size_t)N * 256 * 4 * 2;
    float* al_s1 = (float*)p;            p += (size_t)N * 4 * 4;
    float* al_d1 = (float*)p;            p += (size_t)N * 4 * 4;
    float* al_s2 = (float*)p;            p += (size_t)N * 4;
    float* al_d2 = (float*)p;            p += (size_t)N * 4;
    int* counts  = (int*)p;              p += (size_t)N * 4;
    int* offs    = (int*)p;              p += (size_t)(N + 1) * 4;
    int* cursor  = (int*)p;              p += (size_t)N * 4;
    int* csr_src = (int*)p;              p += (size_t)ET * 4;
    float* h2   = h1;                    // N*64 (reuses dead h1)
    float* out2 = h1 + (size_t)N * 64;   // N*64

    // CSR build
    hipMemsetAsync(counts, 0, (size_t)N * sizeof(int), stream);
    count_edges_k<<<(ET + 255) / 256, 256, 0, stream>>>(ei, counts, E, N);
    scan_k<<<1, 1024, 0, stream>>>(counts, offs, cursor, N);
    fill_csr_k<<<(ET + 255) / 256, 256, 0, stream>>>(ei, cursor, csr_src, E, N);

    // layer 1
    {
        dim3 g((N + 127) / 128, 256 / 128);
        gemm2_k<128, 128, 8, 8><<<g, 256, 0, stream>>>(x, W1, nullptr, h1, N, 256, 256, 0);
    }
    att_k<<<N, 256, 0, stream>>>(h1, as1, ad1, al_s1, al_d1, 4, 64);
    {
        int NH = N * 4;
        gat_agg2_k<4><<<(NH + 3) / 4, 256, 0, stream>>>(h1, al_s1, al_d1, offs, csr_src, b1, out1, 1 * 0 + NH, 1);
    }

    // layer 2
    {
        dim3 g((N + 127) / 128, 1);
        gemm2_k<128, 64, 8, 4><<<g, 256, 0, stream>>>(out1, W2, nullptr, h2, N, 256, 64, 0);
    }
    att_k<<<N, 64, 0, stream>>>(h2, as2, ad2, al_s2, al_d2, 1, 64);
    {
        int NH = N;
        gat_agg2_k<1><<<(NH + 3) / 4, 256, 0, stream>>>(h2, al_s2, al_d2, offs, csr_src, b2, out2, NH, 0);
    }

    // final linear
    {
        dim3 g((N + 127) / 128, 256 / 128);
        gemm2_k<128, 128, 8, 8><<<g, 256, 0, stream>>>(out2, Wf, bf, out, N, 64, 256, 0);
    }
}

// Round 4
// 521.429 us; speedup vs baseline: 1.7620x; 1.0218x over previous
//
#include <hip/hip_runtime.h>
#include <cstddef>
#include <cstdint>

// ---------------- CSR construction ----------------

__global__ void count_edges_k(const int* __restrict__ ei, int* __restrict__ counts,
                              int E, int N) {
    int e = blockIdx.x * blockDim.x + threadIdx.x;
    int tot = E + N;
    if (e >= tot) return;
    int d = (e < E) ? ei[E + e] : (e - E);
    atomicAdd(&counts[d], 1);
}

__global__ __launch_bounds__(1024) void scan_k(const int* __restrict__ counts,
                                               int* __restrict__ offs,
                                               int* __restrict__ cursor, int N) {
    __shared__ int wsum[16];
    __shared__ int carry_s;
    int tid = threadIdx.x, lane = tid & 63, w = tid >> 6;
    if (tid == 0) { carry_s = 0; offs[0] = 0; }
    __syncthreads();
    for (int base = 0; base < N; base += 1024) {
        int i = base + tid;
        int v = (i < N) ? counts[i] : 0;
        int x = v;
        #pragma unroll
        for (int d = 1; d < 64; d <<= 1) {
            int t = __shfl_up(x, d, 64);
            if (lane >= d) x += t;
        }
        if (lane == 63) wsum[w] = x;
        __syncthreads();
        if (tid == 0) {
            int run = 0;
            for (int k = 0; k < 16; k++) { run += wsum[k]; wsum[k] = run; }
        }
        __syncthreads();
        int incl = x + (w > 0 ? wsum[w - 1] : 0) + carry_s;
        if (i < N) { offs[i + 1] = incl; cursor[i] = incl - v; }
        __syncthreads();
        if (tid == 0) carry_s += wsum[15];
        __syncthreads();
    }
}

__global__ void fill_csr_k(const int* __restrict__ ei, int* __restrict__ cursor,
                           int* __restrict__ csr_src, int E, int N) {
    int e = blockIdx.x * blockDim.x + threadIdx.x;
    int tot = E + N;
    if (e >= tot) return;
    int s, d;
    if (e < E) { s = ei[e]; d = ei[E + e]; }
    else       { s = e - E; d = s; }
    int pos = atomicAdd(&cursor[d], 1);
    csr_src[pos] = s;
}

// ---------------- f32 tiled GEMM: C = A[M,K] @ B[K,Nc] (+bias) (+relu) ----------------

template<int BM, int BN, int TM, int TN>
__global__ __launch_bounds__(256) void gemm2_k(const float* __restrict__ A,
                                               const float* __restrict__ B,
                                               const float* __restrict__ bias,
                                               float* __restrict__ C,
                                               int M, int K, int Nc, int relu) {
    const int BK = 16;
    const int RM = TM / 4;
    const int RN = TN / 4;
    const int TX = BN / TN;
    __shared__ float As[BK][BM + 4];
    __shared__ float Bs[BK][BN + 4];

    int bm = blockIdx.x * BM, bn = blockIdx.y * BN;
    int tid = threadIdx.x;
    int tmg = tid / TX;
    int tng = tid % TX;

    float acc[TM][TN] = {};

    for (int k0 = 0; k0 < K; k0 += BK) {
        const int AF4 = BM * BK / 4;
        #pragma unroll
        for (int q0 = 0; q0 < AF4; q0 += 256) {
            int q = q0 + tid;
            int m = q / (BK / 4);
            int kq = q % (BK / 4);
            float4 v = make_float4(0.f, 0.f, 0.f, 0.f);
            if (bm + m < M) v = *(const float4*)&A[(size_t)(bm + m) * K + k0 + kq * 4];
            As[kq * 4 + 0][m] = v.x;
            As[kq * 4 + 1][m] = v.y;
            As[kq * 4 + 2][m] = v.z;
            As[kq * 4 + 3][m] = v.w;
        }
        const int BF4 = BK * BN / 4;
        #pragma unroll
        for (int q0 = 0; q0 < BF4; q0 += 256) {
            int q = q0 + tid;
            int k = q / (BN / 4);
            int c4 = q % (BN / 4);
            *(float4*)&Bs[k][c4 * 4] = *(const float4*)&B[(size_t)(k0 + k) * Nc + bn + c4 * 4];
        }
        __syncthreads();

        #pragma unroll
        for (int k = 0; k < BK; ++k) {
            float a[TM], b[TN];
            #pragma unroll
            for (int r = 0; r < RM; ++r) {
                float4 v = *(const float4*)&As[k][r * (BM / RM) + tmg * 4];
                a[r * 4 + 0] = v.x; a[r * 4 + 1] = v.y;
                a[r * 4 + 2] = v.z; a[r * 4 + 3] = v.w;
            }
            #pragma unroll
            for (int s = 0; s < RN; ++s) {
                float4 v = *(const float4*)&Bs[k][s * (BN / RN) + tng * 4];
                b[s * 4 + 0] = v.x; b[s * 4 + 1] = v.y;
                b[s * 4 + 2] = v.z; b[s * 4 + 3] = v.w;
            }
            #pragma unroll
            for (int i = 0; i < TM; ++i)
                #pragma unroll
                for (int j = 0; j < TN; ++j)
                    acc[i][j] += a[i] * b[j];
        }
        __syncthreads();
    }

    #pragma unroll
    for (int r = 0; r < RM; ++r) {
        #pragma unroll
        for (int i = 0; i < 4; ++i) {
            int m = bm + r * (BM / RM) + tmg * 4 + i;
            if (m >= M) continue;
            #pragma unroll
            for (int s = 0; s < RN; ++s) {
                int n = bn + s * (BN / RN) + tng * 4;
                float4 v;
                v.x = acc[r * 4 + i][s * 4 + 0] + (bias ? bias[n + 0] : 0.f);
                v.y = acc[r * 4 + i][s * 4 + 1] + (bias ? bias[n + 1] : 0.f);
                v.z = acc[r * 4 + i][s * 4 + 2] + (bias ? bias[n + 2] : 0.f);
                v.w = acc[r * 4 + i][s * 4 + 3] + (bias ? bias[n + 3] : 0.f);
                if (relu) {
                    v.x = fmaxf(v.x, 0.f); v.y = fmaxf(v.y, 0.f);
                    v.z = fmaxf(v.z, 0.f); v.w = fmaxf(v.w, 0.f);
                }
                *(float4*)&C[(size_t)m * Nc + n] = v;
            }
        }
    }
}

// ---------------- per-node attention logits ----------------

__global__ void att_k(const float* __restrict__ h, const float* __restrict__ as_,
                      const float* __restrict__ ad_, float* __restrict__ al_s,
                      float* __restrict__ al_d, int H, int C) {
    int n = blockIdx.x;
    int t = threadIdx.x;
    int hd = t / C;
    int c = t % C;
    float hv = h[(size_t)n * H * C + t];
    float ps = hv * as_[t];
    float pd = hv * ad_[t];
    #pragma unroll
    for (int d = 32; d > 0; d >>= 1) {
        ps += __shfl_down(ps, d, 64);
        pd += __shfl_down(pd, d, 64);
    }
    if (c == 0) {
        al_s[(size_t)n * H + hd] = ps;
        al_d[(size_t)n * H + hd] = pd;
    }
}

// ---------------- float4 helpers ----------------

__device__ __forceinline__ float4 shflx4(float4 v, int d) {
    float4 r;
    r.x = __shfl_xor(v.x, d, 64);
    r.y = __shfl_xor(v.y, d, 64);
    r.z = __shfl_xor(v.z, d, 64);
    r.w = __shfl_xor(v.w, d, 64);
    return r;
}
__device__ __forceinline__ float4 max4(float4 a, float4 b) {
    return make_float4(fmaxf(a.x, b.x), fmaxf(a.y, b.y), fmaxf(a.z, b.z), fmaxf(a.w, b.w));
}
__device__ __forceinline__ float sel4(float4 v, int i) {
    float ab = (i & 1) ? v.y : v.x;
    float cd = (i & 1) ? v.w : v.z;
    return (i & 2) ? cd : ab;
}
__device__ __forceinline__ float lrelu(float t) { return (t > 0.f) ? t : 0.2f * t; }

// ---------------- GAT agg, layer 1 (H=4, 256 ch): one wave per NODE ----------------
// Lane owns float4 = 4 channels; 64 lanes = full 1KB row per load instruction.
// All 4 heads' online softmax carried componentwise in float4 registers.

__global__ __launch_bounds__(256) void gat_agg_h4_k(
    const float* __restrict__ h, const float* __restrict__ al_s,
    const float* __restrict__ al_d, const int* __restrict__ offs,
    const int* __restrict__ csr_src, const float* __restrict__ bias,
    float* __restrict__ out, int N)
{
    __shared__ float4 alds[4][64];
    __shared__ int    slds[4][64];
    int w = threadIdx.x >> 6, lane = threadIdx.x & 63;
    int node = blockIdx.x * 4 + w;
    if (node >= N) return;
    int hd = lane >> 4;                       // head owning this lane's 4 channels
    int beg = offs[node], end = offs[node + 1];
    float4 ald4 = *(const float4*)&al_d[(size_t)node * 4];
    float4 m4 = make_float4(-1e30f, -1e30f, -1e30f, -1e30f);
    float4 z4 = make_float4(0.f, 0.f, 0.f, 0.f);
    float4 acc = make_float4(0.f, 0.f, 0.f, 0.f);

    for (int base = beg; base < end; base += 64) {
        int cnt = min(64, end - base);
        int s = 0;
        float4 l4 = make_float4(-1e30f, -1e30f, -1e30f, -1e30f);
        if (lane < cnt) {
            s = csr_src[base + lane];
            float4 as4 = *(const float4*)&al_s[(size_t)s * 4];
            l4.x = lrelu(as4.x + ald4.x);
            l4.y = lrelu(as4.y + ald4.y);
            l4.z = lrelu(as4.z + ald4.z);
            l4.w = lrelu(as4.w + ald4.w);
        }
        float4 mc = l4;
        #pragma unroll
        for (int d = 32; d; d >>= 1) mc = max4(mc, shflx4(mc, d));
        float4 mn = max4(m4, mc);
        float4 p4;
        p4.x = __expf(l4.x - mn.x);           // inactive lanes: exp(-1e30-..) = 0
        p4.y = __expf(l4.y - mn.y);
        p4.z = __expf(l4.z - mn.z);
        p4.w = __expf(l4.w - mn.w);
        float4 zc = p4;
        #pragma unroll
        for (int d = 32; d; d >>= 1) {
            float4 t = shflx4(zc, d);
            zc.x += t.x; zc.y += t.y; zc.z += t.z; zc.w += t.w;
        }
        float4 sc;
        sc.x = __expf(m4.x - mn.x); sc.y = __expf(m4.y - mn.y);
        sc.z = __expf(m4.z - mn.z); sc.w = __expf(m4.w - mn.w);
        z4.x = z4.x * sc.x + zc.x; z4.y = z4.y * sc.y + zc.y;
        z4.z = z4.z * sc.z + zc.z; z4.w = z4.w * sc.w + zc.w;
        float asc = sel4(sc, hd);
        acc.x *= asc; acc.y *= asc; acc.z *= asc; acc.w *= asc;
        alds[w][lane] = p4;
        slds[w][lane] = s;
        #pragma unroll 4
        for (int e = 0; e < cnt; ++e) {
            float a = sel4(alds[w][e], hd);   // 16B LDS broadcast
            int ss = slds[w][e];
            float4 hv = *(const float4*)&h[(size_t)ss * 256 + lane * 4];
            acc.x += a * hv.x; acc.y += a * hv.y;
            acc.z += a * hv.z; acc.w += a * hv.w;
        }
        m4 = mn;
    }

    float rz = 1.f / sel4(z4, hd);
    float4 b4 = *(const float4*)&bias[lane * 4];
    float4 v;
    v.x = fmaxf(acc.x * rz + b4.x, 0.f);
    v.y = fmaxf(acc.y * rz + b4.y, 0.f);
    v.z = fmaxf(acc.z * rz + b4.z, 0.f);
    v.w = fmaxf(acc.w * rz + b4.w, 0.f);
    *(float4*)&out[(size_t)node * 256 + lane * 4] = v;
}

// ---------------- GAT agg, layer 2 (H=1, 64 ch): one wave per node, 4 edges/iter ----------------
// lane = es*16 + c4: 16 lanes x float4 cover the 256B row; 4 edge-subslots in parallel.

__global__ __launch_bounds__(256) void gat_agg_h1_k(
    const float* __restrict__ h, const float* __restrict__ al_s,
    const float* __restrict__ al_d, const int* __restrict__ offs,
    const int* __restrict__ csr_src, const float* __restrict__ bias,
    float* __restrict__ out, int N)
{
    __shared__ float alds[4][64];
    __shared__ int   slds[4][64];
    int w = threadIdx.x >> 6, lane = threadIdx.x & 63;
    int node = blockIdx.x * 4 + w;
    if (node >= N) return;
    int es = lane >> 4, c4 = lane & 15;
    int beg = offs[node], end = offs[node + 1];
    float ald = al_d[node];
    float m_run = -1e30f, z_run = 0.f;
    float4 acc = make_float4(0.f, 0.f, 0.f, 0.f);

    for (int base = beg; base < end; base += 64) {
        int cnt = min(64, end - base);
        int s = 0; float l = -1e30f;
        if (lane < cnt) {
            s = csr_src[base + lane];
            l = lrelu(al_s[s] + ald);
        }
        float mc = l;
        #pragma unroll
        for (int d = 32; d; d >>= 1) mc = fmaxf(mc, __shfl_xor(mc, d, 64));
        float mn = fmaxf(m_run, mc);
        float p = __expf(l - mn);             // 0 for inactive lanes
        float zc = p;
        #pragma unroll
        for (int d = 32; d; d >>= 1) zc += __shfl_xor(zc, d, 64);
        float sc = __expf(m_run - mn);
        z_run = z_run * sc + zc;
        acc.x *= sc; acc.y *= sc; acc.z *= sc; acc.w *= sc;
        alds[w][lane] = p;                    // zeros beyond cnt
        slds[w][lane] = s;
        for (int eb = 0; eb < cnt; eb += 4) {
            int e = eb + es;                  // may exceed cnt; alds there is 0
            float a = alds[w][e];
            int ss = slds[w][e];
            float4 hv = *(const float4*)&h[(size_t)ss * 64 + c4 * 4];
            acc.x += a * hv.x; acc.y += a * hv.y;
            acc.z += a * hv.z; acc.w += a * hv.w;
        }
        m_run = mn;
    }

    // combine the 4 edge-subslot partials
    {
        float4 t = shflx4(acc, 16);
        acc.x += t.x; acc.y += t.y; acc.z += t.z; acc.w += t.w;
        t = shflx4(acc, 32);
        acc.x += t.x; acc.y += t.y; acc.z += t.z; acc.w += t.w;
    }
    if (es == 0) {
        float rz = 1.f / z_run;
        float4 b4 = *(const float4*)&bias[c4 * 4];
        float4 v;
        v.x = acc.x * rz + b4.x;
        v.y = acc.y * rz + b4.y;
        v.z = acc.z * rz + b4.z;
        v.w = acc.w * rz + b4.w;
        *(float4*)&out[(size_t)node * 64 + c4 * 4] = v;
    }
}

// ---------------- launch ----------------

extern "C" void kernel_launch(void* const* d_in, const int* in_sizes, int n_in,
                              void* d_out, int out_size, void* d_ws, size_t ws_size,
                              hipStream_t stream) {
    const float* x   = (const float*)d_in[0];
    const int*   ei  = (const int*)d_in[1];
    const float* W1  = (const float*)d_in[2];
    const float* as1 = (const float*)d_in[3];
    const float* ad1 = (const float*)d_in[4];
    const float* b1  = (const float*)d_in[5];
    const float* W2  = (const float*)d_in[6];
    const float* as2 = (const float*)d_in[7];
    const float* ad2 = (const float*)d_in[8];
    const float* b2  = (const float*)d_in[9];
    const float* Wf  = (const float*)d_in[10];
    const float* bf  = (const float*)d_in[11];
    float* out = (float*)d_out;

    int N = in_sizes[0] / 256;   // 50000
    int E = in_sizes[1] / 2;     // 800000
    int ET = E + N;

    char* w = (char*)d_ws;
    float* h1   = (float*)w;                                  // N*256 f32
    float* out1 = (float*)(w + (size_t)N * 256 * 4);          // N*256 f32
    char*  p    = w + (size_t)N * 256 * 4 * 2;
    float* al_s1 = (float*)p;            p += (size_t)N * 4 * 4;
    float* al_d1 = (float*)p;            p += (size_t)N * 4 * 4;
    float* al_s2 = (float*)p;            p += (size_t)N * 4;
    float* al_d2 = (float*)p;            p += (size_t)N * 4;
    int* counts  = (int*)p;              p += (size_t)N * 4;
    int* offs    = (int*)p;              p += (size_t)(N + 1) * 4;
    int* cursor  = (int*)p;              p += (size_t)N * 4;
    int* csr_src = (int*)p;              p += (size_t)ET * 4;
    float* h2   = h1;                    // N*64 (reuses dead h1)
    float* out2 = h1 + (size_t)N * 64;   // N*64

    // CSR build
    hipMemsetAsync(counts, 0, (size_t)N * sizeof(int), stream);
    count_edges_k<<<(ET + 255) / 256, 256, 0, stream>>>(ei, counts, E, N);
    scan_k<<<1, 1024, 0, stream>>>(counts, offs, cursor, N);
    fill_csr_k<<<(ET + 255) / 256, 256, 0, stream>>>(ei, cursor, csr_src, E, N);

    // layer 1
    {
        dim3 g((N + 127) / 128, 256 / 128);
        gemm2_k<128, 128, 8, 8><<<g, 256, 0, stream>>>(x, W1, nullptr, h1, N, 256, 256, 0);
    }
    att_k<<<N, 256, 0, stream>>>(h1, as1, ad1, al_s1, al_d1, 4, 64);
    gat_agg_h4_k<<<(N + 3) / 4, 256, 0, stream>>>(h1, al_s1, al_d1, offs, csr_src, b1, out1, N);

    // layer 2
    {
        dim3 g((N + 127) / 128, 1);
        gemm2_k<128, 64, 8, 4><<<g, 256, 0, stream>>>(out1, W2, nullptr, h2, N, 256, 64, 0);
    }
    att_k<<<N, 64, 0, stream>>>(h2, as2, ad2, al_s2, al_d2, 1, 64);
    gat_agg_h1_k<<<(N + 3) / 4, 256, 0, stream>>>(h2, al_s2, al_d2, offs, csr_src, b2, out2, N);

    // final linear
    {
        dim3 g((N + 127) / 128, 256 / 128);
        gemm2_k<128, 128, 8, 8><<<g, 256, 0, stream>>>(out2, Wf, bf, out, N, 64, 256, 0);
    }
}

// Round 5
// 479.077 us; speedup vs baseline: 1.9177x; 1.0884x over previous
//
#include <hip/hip_runtime.h>
#include <cstddef>
#include <cstdint>

// ---------------- bf16 helpers ----------------

__device__ __forceinline__ unsigned short f2bf(float f) {
    // round-to-nearest-even f32 -> bf16 (values here are tame: no NaN/Inf handling needed)
    uint32_t u = __float_as_uint(f);
    u += 0x7FFFu + ((u >> 16) & 1u);
    return (unsigned short)(u >> 16);
}
__device__ __forceinline__ float bf2f(unsigned short b) {
    return __uint_as_float(((uint32_t)b) << 16);
}

// ---------------- CSR construction ----------------

__global__ void count_edges_k(const int* __restrict__ ei, int* __restrict__ counts,
                              int E, int N) {
    int e = blockIdx.x * blockDim.x + threadIdx.x;
    int tot = E + N;
    if (e >= tot) return;
    int d = (e < E) ? ei[E + e] : (e - E);
    atomicAdd(&counts[d], 1);
}

__global__ __launch_bounds__(1024) void scan_k(const int* __restrict__ counts,
                                               int* __restrict__ offs,
                                               int* __restrict__ cursor, int N) {
    __shared__ int wsum[16];
    __shared__ int carry_s;
    int tid = threadIdx.x, lane = tid & 63, w = tid >> 6;
    if (tid == 0) { carry_s = 0; offs[0] = 0; }
    __syncthreads();
    for (int base = 0; base < N; base += 1024) {
        int i = base + tid;
        int v = (i < N) ? counts[i] : 0;
        int x = v;
        #pragma unroll
        for (int d = 1; d < 64; d <<= 1) {
            int t = __shfl_up(x, d, 64);
            if (lane >= d) x += t;
        }
        if (lane == 63) wsum[w] = x;
        __syncthreads();
        if (tid == 0) {
            int run = 0;
            for (int k = 0; k < 16; k++) { run += wsum[k]; wsum[k] = run; }
        }
        __syncthreads();
        int incl = x + (w > 0 ? wsum[w - 1] : 0) + carry_s;
        if (i < N) { offs[i + 1] = incl; cursor[i] = incl - v; }
        __syncthreads();
        if (tid == 0) carry_s += wsum[15];
        __syncthreads();
    }
}

__global__ void fill_csr_k(const int* __restrict__ ei, int* __restrict__ cursor,
                           int* __restrict__ csr_src, int E, int N) {
    int e = blockIdx.x * blockDim.x + threadIdx.x;
    int tot = E + N;
    if (e >= tot) return;
    int s, d;
    if (e < E) { s = ei[e]; d = ei[E + e]; }
    else       { s = e - E; d = s; }
    int pos = atomicAdd(&cursor[d], 1);
    csr_src[pos] = s;
}

// ---------------- f32 tiled GEMM: C = A[M,K] @ B[K,Nc] (+bias) (+relu) ----------------
// OUTB=1: emit bf16 (RNE) instead of f32.

template<int BM, int BN, int TM, int TN, bool OUTB>
__global__ __launch_bounds__(256) void gemm2_k(const float* __restrict__ A,
                                               const float* __restrict__ B,
                                               const float* __restrict__ bias,
                                               float* __restrict__ Cf,
                                               unsigned short* __restrict__ Cb,
                                               int M, int K, int Nc, int relu) {
    const int BK = 16;
    const int RM = TM / 4;
    const int RN = TN / 4;
    const int TX = BN / TN;
    __shared__ float As[BK][BM + 4];
    __shared__ float Bs[BK][BN + 4];

    int bm = blockIdx.x * BM, bn = blockIdx.y * BN;
    int tid = threadIdx.x;
    int tmg = tid / TX;
    int tng = tid % TX;

    float acc[TM][TN] = {};

    for (int k0 = 0; k0 < K; k0 += BK) {
        const int AF4 = BM * BK / 4;
        #pragma unroll
        for (int q0 = 0; q0 < AF4; q0 += 256) {
            int q = q0 + tid;
            int m = q / (BK / 4);
            int kq = q % (BK / 4);
            float4 v = make_float4(0.f, 0.f, 0.f, 0.f);
            if (bm + m < M) v = *(const float4*)&A[(size_t)(bm + m) * K + k0 + kq * 4];
            As[kq * 4 + 0][m] = v.x;
            As[kq * 4 + 1][m] = v.y;
            As[kq * 4 + 2][m] = v.z;
            As[kq * 4 + 3][m] = v.w;
        }
        const int BF4 = BK * BN / 4;
        #pragma unroll
        for (int q0 = 0; q0 < BF4; q0 += 256) {
            int q = q0 + tid;
            int k = q / (BN / 4);
            int c4 = q % (BN / 4);
            *(float4*)&Bs[k][c4 * 4] = *(const float4*)&B[(size_t)(k0 + k) * Nc + bn + c4 * 4];
        }
        __syncthreads();

        #pragma unroll
        for (int k = 0; k < BK; ++k) {
            float a[TM], b[TN];
            #pragma unroll
            for (int r = 0; r < RM; ++r) {
                float4 v = *(const float4*)&As[k][r * (BM / RM) + tmg * 4];
                a[r * 4 + 0] = v.x; a[r * 4 + 1] = v.y;
                a[r * 4 + 2] = v.z; a[r * 4 + 3] = v.w;
            }
            #pragma unroll
            for (int s = 0; s < RN; ++s) {
                float4 v = *(const float4*)&Bs[k][s * (BN / RN) + tng * 4];
                b[s * 4 + 0] = v.x; b[s * 4 + 1] = v.y;
                b[s * 4 + 2] = v.z; b[s * 4 + 3] = v.w;
            }
            #pragma unroll
            for (int i = 0; i < TM; ++i)
                #pragma unroll
                for (int j = 0; j < TN; ++j)
                    acc[i][j] += a[i] * b[j];
        }
        __syncthreads();
    }

    #pragma unroll
    for (int r = 0; r < RM; ++r) {
        #pragma unroll
        for (int i = 0; i < 4; ++i) {
            int m = bm + r * (BM / RM) + tmg * 4 + i;
            if (m >= M) continue;
            #pragma unroll
            for (int s = 0; s < RN; ++s) {
                int n = bn + s * (BN / RN) + tng * 4;
                float4 v;
                v.x = acc[r * 4 + i][s * 4 + 0] + (bias ? bias[n + 0] : 0.f);
                v.y = acc[r * 4 + i][s * 4 + 1] + (bias ? bias[n + 1] : 0.f);
                v.z = acc[r * 4 + i][s * 4 + 2] + (bias ? bias[n + 2] : 0.f);
                v.w = acc[r * 4 + i][s * 4 + 3] + (bias ? bias[n + 3] : 0.f);
                if (relu) {
                    v.x = fmaxf(v.x, 0.f); v.y = fmaxf(v.y, 0.f);
                    v.z = fmaxf(v.z, 0.f); v.w = fmaxf(v.w, 0.f);
                }
                if (OUTB) {
                    ushort4 pb;
                    pb.x = f2bf(v.x); pb.y = f2bf(v.y);
                    pb.z = f2bf(v.z); pb.w = f2bf(v.w);
                    *(ushort4*)&Cb[(size_t)m * Nc + n] = pb;
                } else {
                    *(float4*)&Cf[(size_t)m * Nc + n] = v;
                }
            }
        }
    }
}

// ---------------- per-node attention logits (f32 input) ----------------

__global__ void att_k(const float* __restrict__ h, const float* __restrict__ as_,
                      const float* __restrict__ ad_, float* __restrict__ al_s,
                      float* __restrict__ al_d, int H, int C) {
    int n = blockIdx.x;
    int t = threadIdx.x;
    int hd = t / C;
    int c = t % C;
    float hv = h[(size_t)n * H * C + t];
    float ps = hv * as_[t];
    float pd = hv * ad_[t];
    #pragma unroll
    for (int d = 32; d > 0; d >>= 1) {
        ps += __shfl_down(ps, d, 64);
        pd += __shfl_down(pd, d, 64);
    }
    if (c == 0) {
        al_s[(size_t)n * H + hd] = ps;
        al_d[(size_t)n * H + hd] = pd;
    }
}

// ---------------- per-node attention logits (bf16 input) ----------------

__global__ void att_b_k(const unsigned short* __restrict__ hb, const float* __restrict__ as_,
                        const float* __restrict__ ad_, float* __restrict__ al_s,
                        float* __restrict__ al_d, int H, int C) {
    int n = blockIdx.x;
    int t = threadIdx.x;
    int hd = t / C;
    int c = t % C;
    float hv = bf2f(hb[(size_t)n * H * C + t]);
    float ps = hv * as_[t];
    float pd = hv * ad_[t];
    #pragma unroll
    for (int d = 32; d > 0; d >>= 1) {
        ps += __shfl_down(ps, d, 64);
        pd += __shfl_down(pd, d, 64);
    }
    if (c == 0) {
        al_s[(size_t)n * H + hd] = ps;
        al_d[(size_t)n * H + hd] = pd;
    }
}

// ---------------- float4 helpers ----------------

__device__ __forceinline__ float4 shflx4(float4 v, int d) {
    float4 r;
    r.x = __shfl_xor(v.x, d, 64);
    r.y = __shfl_xor(v.y, d, 64);
    r.z = __shfl_xor(v.z, d, 64);
    r.w = __shfl_xor(v.w, d, 64);
    return r;
}
__device__ __forceinline__ float4 max4(float4 a, float4 b) {
    return make_float4(fmaxf(a.x, b.x), fmaxf(a.y, b.y), fmaxf(a.z, b.z), fmaxf(a.w, b.w));
}
__device__ __forceinline__ float sel4(float4 v, int i) {
    float ab = (i & 1) ? v.y : v.x;
    float cd = (i & 1) ? v.w : v.z;
    return (i & 2) ? cd : ab;
}
__device__ __forceinline__ float lrelu(float t) { return (t > 0.f) ? t : 0.2f * t; }

// ---------------- GAT agg, layer 1 (H=4, 256 ch, bf16 payload): one wave per NODE ----------------
// Lane owns 4 channels (8B bf16); 64 lanes = full 512B row per load instruction.

__global__ __launch_bounds__(256) void gat_agg_h4b_k(
    const unsigned short* __restrict__ hb, const float* __restrict__ al_s,
    const float* __restrict__ al_d, const int* __restrict__ offs,
    const int* __restrict__ csr_src, const float* __restrict__ bias,
    float* __restrict__ out, int N)
{
    __shared__ float4 alds[4][64];
    __shared__ int    slds[4][64];
    int w = threadIdx.x >> 6, lane = threadIdx.x & 63;
    int node = blockIdx.x * 4 + w;
    if (node >= N) return;
    int hd = lane >> 4;
    int beg = offs[node], end = offs[node + 1];
    float4 ald4 = *(const float4*)&al_d[(size_t)node * 4];
    float4 m4 = make_float4(-1e30f, -1e30f, -1e30f, -1e30f);
    float4 z4 = make_float4(0.f, 0.f, 0.f, 0.f);
    float4 acc = make_float4(0.f, 0.f, 0.f, 0.f);

    for (int base = beg; base < end; base += 64) {
        int cnt = min(64, end - base);
        int s = 0;
        float4 l4 = make_float4(-1e30f, -1e30f, -1e30f, -1e30f);
        if (lane < cnt) {
            s = csr_src[base + lane];
            float4 as4 = *(const float4*)&al_s[(size_t)s * 4];
            l4.x = lrelu(as4.x + ald4.x);
            l4.y = lrelu(as4.y + ald4.y);
            l4.z = lrelu(as4.z + ald4.z);
            l4.w = lrelu(as4.w + ald4.w);
        }
        float4 mc = l4;
        #pragma unroll
        for (int d = 32; d; d >>= 1) mc = max4(mc, shflx4(mc, d));
        float4 mn = max4(m4, mc);
        float4 p4;
        p4.x = __expf(l4.x - mn.x);
        p4.y = __expf(l4.y - mn.y);
        p4.z = __expf(l4.z - mn.z);
        p4.w = __expf(l4.w - mn.w);
        float4 zc = p4;
        #pragma unroll
        for (int d = 32; d; d >>= 1) {
            float4 t = shflx4(zc, d);
            zc.x += t.x; zc.y += t.y; zc.z += t.z; zc.w += t.w;
        }
        float4 sc;
        sc.x = __expf(m4.x - mn.x); sc.y = __expf(m4.y - mn.y);
        sc.z = __expf(m4.z - mn.z); sc.w = __expf(m4.w - mn.w);
        z4.x = z4.x * sc.x + zc.x; z4.y = z4.y * sc.y + zc.y;
        z4.z = z4.z * sc.z + zc.z; z4.w = z4.w * sc.w + zc.w;
        float asc = sel4(sc, hd);
        acc.x *= asc; acc.y *= asc; acc.z *= asc; acc.w *= asc;
        alds[w][lane] = p4;
        slds[w][lane] = s;
        #pragma unroll 4
        for (int e = 0; e < cnt; ++e) {
            float a = sel4(alds[w][e], hd);
            int ss = slds[w][e];
            ushort4 hv = *(const ushort4*)&hb[(size_t)ss * 256 + lane * 4];
            acc.x += a * bf2f(hv.x); acc.y += a * bf2f(hv.y);
            acc.z += a * bf2f(hv.z); acc.w += a * bf2f(hv.w);
        }
        m4 = mn;
    }

    float rz = 1.f / sel4(z4, hd);
    float4 b4 = *(const float4*)&bias[lane * 4];
    float4 v;
    v.x = fmaxf(acc.x * rz + b4.x, 0.f);
    v.y = fmaxf(acc.y * rz + b4.y, 0.f);
    v.z = fmaxf(acc.z * rz + b4.z, 0.f);
    v.w = fmaxf(acc.w * rz + b4.w, 0.f);
    *(float4*)&out[(size_t)node * 256 + lane * 4] = v;
}

// ---------------- GAT agg, layer 2 (H=1, 64 ch, f32): one wave per node, 4 edges/iter ----------------

__global__ __launch_bounds__(256) void gat_agg_h1_k(
    const float* __restrict__ h, const float* __restrict__ al_s,
    const float* __restrict__ al_d, const int* __restrict__ offs,
    const int* __restrict__ csr_src, const float* __restrict__ bias,
    float* __restrict__ out, int N)
{
    __shared__ float alds[4][64];
    __shared__ int   slds[4][64];
    int w = threadIdx.x >> 6, lane = threadIdx.x & 63;
    int node = blockIdx.x * 4 + w;
    if (node >= N) return;
    int es = lane >> 4, c4 = lane & 15;
    int beg = offs[node], end = offs[node + 1];
    float ald = al_d[node];
    float m_run = -1e30f, z_run = 0.f;
    float4 acc = make_float4(0.f, 0.f, 0.f, 0.f);

    for (int base = beg; base < end; base += 64) {
        int cnt = min(64, end - base);
        int s = 0; float l = -1e30f;
        if (lane < cnt) {
            s = csr_src[base + lane];
            l = lrelu(al_s[s] + ald);
        }
        float mc = l;
        #pragma unroll
        for (int d = 32; d; d >>= 1) mc = fmaxf(mc, __shfl_xor(mc, d, 64));
        float mn = fmaxf(m_run, mc);
        float p = __expf(l - mn);
        float zc = p;
        #pragma unroll
        for (int d = 32; d; d >>= 1) zc += __shfl_xor(zc, d, 64);
        float sc = __expf(m_run - mn);
        z_run = z_run * sc + zc;
        acc.x *= sc; acc.y *= sc; acc.z *= sc; acc.w *= sc;
        alds[w][lane] = p;
        slds[w][lane] = s;
        for (int eb = 0; eb < cnt; eb += 4) {
            int e = eb + es;
            float a = alds[w][e];
            int ss = slds[w][e];
            float4 hv = *(const float4*)&h[(size_t)ss * 64 + c4 * 4];
            acc.x += a * hv.x; acc.y += a * hv.y;
            acc.z += a * hv.z; acc.w += a * hv.w;
        }
        m_run = mn;
    }

    {
        float4 t = shflx4(acc, 16);
        acc.x += t.x; acc.y += t.y; acc.z += t.z; acc.w += t.w;
        t = shflx4(acc, 32);
        acc.x += t.x; acc.y += t.y; acc.z += t.z; acc.w += t.w;
    }
    if (es == 0) {
        float rz = 1.f / z_run;
        float4 b4 = *(const float4*)&bias[c4 * 4];
        float4 v;
        v.x = acc.x * rz + b4.x;
        v.y = acc.y * rz + b4.y;
        v.z = acc.z * rz + b4.z;
        v.w = acc.w * rz + b4.w;
        *(float4*)&out[(size_t)node * 64 + c4 * 4] = v;
    }
}

// ---------------- launch ----------------

extern "C" void kernel_launch(void* const* d_in, const int* in_sizes, int n_in,
                              void* d_out, int out_size, void* d_ws, size_t ws_size,
                              hipStream_t stream) {
    const float* x   = (const float*)d_in[0];
    const int*   ei  = (const int*)d_in[1];
    const float* W1  = (const float*)d_in[2];
    const float* as1 = (const float*)d_in[3];
    const float* ad1 = (const float*)d_in[4];
    const float* b1  = (const float*)d_in[5];
    const float* W2  = (const float*)d_in[6];
    const float* as2 = (const float*)d_in[7];
    const float* ad2 = (const float*)d_in[8];
    const float* b2  = (const float*)d_in[9];
    const float* Wf  = (const float*)d_in[10];
    const float* bf  = (const float*)d_in[11];
    float* out = (float*)d_out;

    int N = in_sizes[0] / 256;   // 50000
    int E = in_sizes[1] / 2;     // 800000
    int ET = E + N;

    char* w = (char*)d_ws;
    float* big  = (float*)w;                                  // N*256 f32 (h2/out2 live here)
    float* out1 = (float*)(w + (size_t)N * 256 * 4);          // N*256 f32
    char*  p    = w + (size_t)N * 256 * 4 * 2;
    unsigned short* h1b = (unsigned short*)p;  p += (size_t)N * 256 * 2;   // bf16 h1
    float* al_s1 = (float*)p;            p += (size_t)N * 4 * 4;
    float* al_d1 = (float*)p;            p += (size_t)N * 4 * 4;
    float* al_s2 = (float*)p;            p += (size_t)N * 4;
    float* al_d2 = (float*)p;            p += (size_t)N * 4;
    int* counts  = (int*)p;              p += (size_t)N * 4;
    int* offs    = (int*)p;              p += (size_t)(N + 1) * 4;
    int* cursor  = (int*)p;              p += (size_t)N * 4;
    int* csr_src = (int*)p;              p += (size_t)ET * 4;
    float* h2   = big;                   // N*64 f32
    float* out2 = big + (size_t)N * 64;  // N*64 f32

    // CSR build
    hipMemsetAsync(counts, 0, (size_t)N * sizeof(int), stream);
    count_edges_k<<<(ET + 255) / 256, 256, 0, stream>>>(ei, counts, E, N);
    scan_k<<<1, 1024, 0, stream>>>(counts, offs, cursor, N);
    fill_csr_k<<<(ET + 255) / 256, 256, 0, stream>>>(ei, cursor, csr_src, E, N);

    // layer 1 (bf16 h)
    {
        dim3 g((N + 127) / 128, 256 / 128);
        gemm2_k<128, 128, 8, 8, true><<<g, 256, 0, stream>>>(x, W1, nullptr, nullptr, h1b, N, 256, 256, 0);
    }
    att_b_k<<<N, 256, 0, stream>>>(h1b, as1, ad1, al_s1, al_d1, 4, 64);
    gat_agg_h4b_k<<<(N + 3) / 4, 256, 0, stream>>>(h1b, al_s1, al_d1, offs, csr_src, b1, out1, N);

    // layer 2 (f32)
    {
        dim3 g((N + 127) / 128, 1);
        gemm2_k<128, 64, 8, 4, false><<<g, 256, 0, stream>>>(out1, W2, nullptr, h2, nullptr, N, 256, 64, 0);
    }
    att_k<<<N, 64, 0, stream>>>(h2, as2, ad2, al_s2, al_d2, 1, 64);
    gat_agg_h1_k<<<(N + 3) / 4, 256, 0, stream>>>(h2, al_s2, al_d2, offs, csr_src, b2, out2, N);

    // final linear
    {
        dim3 g((N + 127) / 128, 256 / 128);
        gemm2_k<128, 128, 8, 8, false><<<g, 256, 0, stream>>>(out2, Wf, bf, out, nullptr, N, 64, 256, 0);
    }
}

// Round 6
// 409.269 us; speedup vs baseline: 2.2448x; 1.1706x over previous
//
#include <hip/hip_runtime.h>
#include <cstddef>
#include <cstdint>

// ---------------- bf16 helpers ----------------

__device__ __forceinline__ unsigned short f2bf(float f) {
    uint32_t u = __float_as_uint(f);
    u += 0x7FFFu + ((u >> 16) & 1u);
    return (unsigned short)(u >> 16);
}
__device__ __forceinline__ float bf2f(unsigned short b) {
    return __uint_as_float(((uint32_t)b) << 16);
}

typedef __attribute__((ext_vector_type(8))) short bf16x8;
typedef __attribute__((ext_vector_type(4))) float f32x4;

// ---------------- CSR construction ----------------

__global__ void count_edges_k(const int* __restrict__ ei, int* __restrict__ counts,
                              int E, int N) {
    int e = blockIdx.x * blockDim.x + threadIdx.x;
    int tot = E + N;
    if (e >= tot) return;
    int d = (e < E) ? ei[E + e] : (e - E);
    atomicAdd(&counts[d], 1);
}

__global__ __launch_bounds__(1024) void scan_k(const int* __restrict__ counts,
                                               int* __restrict__ offs,
                                               int* __restrict__ cursor, int N) {
    __shared__ int wsum[16];
    __shared__ int carry_s;
    int tid = threadIdx.x, lane = tid & 63, w = tid >> 6;
    if (tid == 0) { carry_s = 0; offs[0] = 0; }
    __syncthreads();
    for (int base = 0; base < N; base += 1024) {
        int i = base + tid;
        int v = (i < N) ? counts[i] : 0;
        int x = v;
        #pragma unroll
        for (int d = 1; d < 64; d <<= 1) {
            int t = __shfl_up(x, d, 64);
            if (lane >= d) x += t;
        }
        if (lane == 63) wsum[w] = x;
        __syncthreads();
        if (tid == 0) {
            int run = 0;
            for (int k = 0; k < 16; k++) { run += wsum[k]; wsum[k] = run; }
        }
        __syncthreads();
        int incl = x + (w > 0 ? wsum[w - 1] : 0) + carry_s;
        if (i < N) { offs[i + 1] = incl; cursor[i] = incl - v; }
        __syncthreads();
        if (tid == 0) carry_s += wsum[15];
        __syncthreads();
    }
}

__global__ void fill_csr_k(const int* __restrict__ ei, int* __restrict__ cursor,
                           int* __restrict__ csr_src, int E, int N) {
    int e = blockIdx.x * blockDim.x + threadIdx.x;
    int tot = E + N;
    if (e >= tot) return;
    int s, d;
    if (e < E) { s = ei[e]; d = ei[E + e]; }
    else       { s = e - E; d = s; }
    int pos = atomicAdd(&cursor[d], 1);
    csr_src[pos] = s;
}

// ---------------- converts ----------------

__global__ void f2bf4_k(const float* __restrict__ in, unsigned short* __restrict__ out, int n4) {
    int i = blockIdx.x * blockDim.x + threadIdx.x;
    if (i >= n4) return;
    float4 v = ((const float4*)in)[i];
    ushort4 o;
    o.x = f2bf(v.x); o.y = f2bf(v.y); o.z = f2bf(v.z); o.w = f2bf(v.w);
    ((ushort4*)out)[i] = o;
}

// W1 [K=256][N=256] f32 -> W1bT [N][K] bf16
__global__ void w1t_k(const float* __restrict__ W, unsigned short* __restrict__ WT) {
    int n = blockIdx.x;     // 256 blocks
    int k = threadIdx.x;    // 256 threads
    WT[n * 256 + k] = f2bf(W[k * 256 + n]);
}

// ---------------- MFMA bf16 GEMM (GEMM1): C[M,256] = A[M,256] @ B[256,256] ----------------
// 128x128 tile, 4 waves (2x2 of 64x64), BK=32, bf16 in, bf16 out (RNE).
// LDS tiles [row][k] padded to stride 40 bf16 (80B = 5*16B: b128-aligned, uniform banks).

__global__ __launch_bounds__(256) void gemm_mfma1_k(
    const unsigned short* __restrict__ Ab,   // [M][256] bf16
    const unsigned short* __restrict__ BT,   // [256][256] bf16, BT[n][k]
    unsigned short* __restrict__ Cb,         // [M][256] bf16
    int M)
{
    const int SA = 40;
    __shared__ unsigned short As[128 * SA];
    __shared__ unsigned short Bs[128 * SA];
    int tid = threadIdx.x;
    int lane = tid & 63, wid = tid >> 6;
    int wm = wid >> 1, wn = wid & 1;
    int bm = blockIdx.x * 128, bn = blockIdx.y * 128;

    f32x4 acc[4][4];
    #pragma unroll
    for (int mi = 0; mi < 4; ++mi)
        #pragma unroll
        for (int ni = 0; ni < 4; ++ni) {
            acc[mi][ni][0] = 0.f; acc[mi][ni][1] = 0.f;
            acc[mi][ni][2] = 0.f; acc[mi][ni][3] = 0.f;
        }

    int srow = tid >> 2;       // 0..63
    int skc  = tid & 3;        // 0..3 (8-bf16 chunk within BK=32)

    for (int k0 = 0; k0 < 256; k0 += 32) {
        #pragma unroll
        for (int q = 0; q < 2; ++q) {
            int row = q * 64 + srow;
            int4 av = make_int4(0, 0, 0, 0);
            int gr = bm + row;
            if (gr < M) av = *(const int4*)&Ab[(size_t)gr * 256 + k0 + skc * 8];
            *(int4*)&As[row * SA + skc * 8] = av;
            int4 bv = *(const int4*)&BT[(size_t)(bn + row) * 256 + k0 + skc * 8];
            *(int4*)&Bs[row * SA + skc * 8] = bv;
        }
        __syncthreads();

        bf16x8 af[4], bfv[4];
        #pragma unroll
        for (int mi = 0; mi < 4; ++mi)
            af[mi] = *(const bf16x8*)&As[(wm * 64 + mi * 16 + (lane & 15)) * SA + (lane >> 4) * 8];
        #pragma unroll
        for (int ni = 0; ni < 4; ++ni)
            bfv[ni] = *(const bf16x8*)&Bs[(wn * 64 + ni * 16 + (lane & 15)) * SA + (lane >> 4) * 8];
        #pragma unroll
        for (int mi = 0; mi < 4; ++mi)
            #pragma unroll
            for (int ni = 0; ni < 4; ++ni)
                acc[mi][ni] = __builtin_amdgcn_mfma_f32_16x16x32_bf16(af[mi], bfv[ni], acc[mi][ni], 0, 0, 0);
        __syncthreads();
    }

    // epilogue: D col = lane&15, row = (lane>>4)*4 + reg
    #pragma unroll
    for (int mi = 0; mi < 4; ++mi) {
        #pragma unroll
        for (int j = 0; j < 4; ++j) {
            int row = bm + wm * 64 + mi * 16 + (lane >> 4) * 4 + j;
            if (row >= M) continue;
            #pragma unroll
            for (int ni = 0; ni < 4; ++ni) {
                int col = bn + wn * 64 + ni * 16 + (lane & 15);
                Cb[(size_t)row * 256 + col] = f2bf(acc[mi][ni][j]);
            }
        }
    }
}

// ---------------- f32 tiled GEMM: C = A[M,K] @ B[K,Nc] (+bias) (+relu) ----------------

template<int BM, int BN, int TM, int TN, bool OUTB>
__global__ __launch_bounds__(256) void gemm2_k(const float* __restrict__ A,
                                               const float* __restrict__ B,
                                               const float* __restrict__ bias,
                                               float* __restrict__ Cf,
                                               unsigned short* __restrict__ Cb,
                                               int M, int K, int Nc, int relu) {
    const int BK = 16;
    const int RM = TM / 4;
    const int RN = TN / 4;
    const int TX = BN / TN;
    __shared__ float As[BK][BM + 4];
    __shared__ float Bs[BK][BN + 4];

    int bm = blockIdx.x * BM, bn = blockIdx.y * BN;
    int tid = threadIdx.x;
    int tmg = tid / TX;
    int tng = tid % TX;

    float acc[TM][TN] = {};

    for (int k0 = 0; k0 < K; k0 += BK) {
        const int AF4 = BM * BK / 4;
        #pragma unroll
        for (int q0 = 0; q0 < AF4; q0 += 256) {
            int q = q0 + tid;
            int m = q / (BK / 4);
            int kq = q % (BK / 4);
            float4 v = make_float4(0.f, 0.f, 0.f, 0.f);
            if (bm + m < M) v = *(const float4*)&A[(size_t)(bm + m) * K + k0 + kq * 4];
            As[kq * 4 + 0][m] = v.x;
            As[kq * 4 + 1][m] = v.y;
            As[kq * 4 + 2][m] = v.z;
            As[kq * 4 + 3][m] = v.w;
        }
        const int BF4 = BK * BN / 4;
        #pragma unroll
        for (int q0 = 0; q0 < BF4; q0 += 256) {
            int q = q0 + tid;
            int k = q / (BN / 4);
            int c4 = q % (BN / 4);
            *(float4*)&Bs[k][c4 * 4] = *(const float4*)&B[(size_t)(k0 + k) * Nc + bn + c4 * 4];
        }
        __syncthreads();

        #pragma unroll
        for (int k = 0; k < BK; ++k) {
            float a[TM], b[TN];
            #pragma unroll
            for (int r = 0; r < RM; ++r) {
                float4 v = *(const float4*)&As[k][r * (BM / RM) + tmg * 4];
                a[r * 4 + 0] = v.x; a[r * 4 + 1] = v.y;
                a[r * 4 + 2] = v.z; a[r * 4 + 3] = v.w;
            }
            #pragma unroll
            for (int s = 0; s < RN; ++s) {
                float4 v = *(const float4*)&Bs[k][s * (BN / RN) + tng * 4];
                b[s * 4 + 0] = v.x; b[s * 4 + 1] = v.y;
                b[s * 4 + 2] = v.z; b[s * 4 + 3] = v.w;
            }
            #pragma unroll
            for (int i = 0; i < TM; ++i)
                #pragma unroll
                for (int j = 0; j < TN; ++j)
                    acc[i][j] += a[i] * b[j];
        }
        __syncthreads();
    }

    #pragma unroll
    for (int r = 0; r < RM; ++r) {
        #pragma unroll
        for (int i = 0; i < 4; ++i) {
            int m = bm + r * (BM / RM) + tmg * 4 + i;
            if (m >= M) continue;
            #pragma unroll
            for (int s = 0; s < RN; ++s) {
                int n = bn + s * (BN / RN) + tng * 4;
                float4 v;
                v.x = acc[r * 4 + i][s * 4 + 0] + (bias ? bias[n + 0] : 0.f);
                v.y = acc[r * 4 + i][s * 4 + 1] + (bias ? bias[n + 1] : 0.f);
                v.z = acc[r * 4 + i][s * 4 + 2] + (bias ? bias[n + 2] : 0.f);
                v.w = acc[r * 4 + i][s * 4 + 3] + (bias ? bias[n + 3] : 0.f);
                if (relu) {
                    v.x = fmaxf(v.x, 0.f); v.y = fmaxf(v.y, 0.f);
                    v.z = fmaxf(v.z, 0.f); v.w = fmaxf(v.w, 0.f);
                }
                if (OUTB) {
                    ushort4 pb;
                    pb.x = f2bf(v.x); pb.y = f2bf(v.y);
                    pb.z = f2bf(v.z); pb.w = f2bf(v.w);
                    *(ushort4*)&Cb[(size_t)m * Nc + n] = pb;
                } else {
                    *(float4*)&Cf[(size_t)m * Nc + n] = v;
                }
            }
        }
    }
}

// ---------------- per-node attention logits (f32 input) ----------------

__global__ void att_k(const float* __restrict__ h, const float* __restrict__ as_,
                      const float* __restrict__ ad_, float* __restrict__ al_s,
                      float* __restrict__ al_d, int H, int C) {
    int n = blockIdx.x;
    int t = threadIdx.x;
    int hd = t / C;
    int c = t % C;
    float hv = h[(size_t)n * H * C + t];
    float ps = hv * as_[t];
    float pd = hv * ad_[t];
    #pragma unroll
    for (int d = 32; d > 0; d >>= 1) {
        ps += __shfl_down(ps, d, 64);
        pd += __shfl_down(pd, d, 64);
    }
    if (c == 0) {
        al_s[(size_t)n * H + hd] = ps;
        al_d[(size_t)n * H + hd] = pd;
    }
}

// ---------------- per-node attention logits (bf16 input) ----------------

__global__ void att_b_k(const unsigned short* __restrict__ hb, const float* __restrict__ as_,
                        const float* __restrict__ ad_, float* __restrict__ al_s,
                        float* __restrict__ al_d, int H, int C) {
    int n = blockIdx.x;
    int t = threadIdx.x;
    int hd = t / C;
    int c = t % C;
    float hv = bf2f(hb[(size_t)n * H * C + t]);
    float ps = hv * as_[t];
    float pd = hv * ad_[t];
    #pragma unroll
    for (int d = 32; d > 0; d >>= 1) {
        ps += __shfl_down(ps, d, 64);
        pd += __shfl_down(pd, d, 64);
    }
    if (c == 0) {
        al_s[(size_t)n * H + hd] = ps;
        al_d[(size_t)n * H + hd] = pd;
    }
}

// ---------------- float4 helpers ----------------

__device__ __forceinline__ float4 shflx4(float4 v, int d) {
    float4 r;
    r.x = __shfl_xor(v.x, d, 64);
    r.y = __shfl_xor(v.y, d, 64);
    r.z = __shfl_xor(v.z, d, 64);
    r.w = __shfl_xor(v.w, d, 64);
    return r;
}
__device__ __forceinline__ float4 max4(float4 a, float4 b) {
    return make_float4(fmaxf(a.x, b.x), fmaxf(a.y, b.y), fmaxf(a.z, b.z), fmaxf(a.w, b.w));
}
__device__ __forceinline__ float sel4(float4 v, int i) {
    float ab = (i & 1) ? v.y : v.x;
    float cd = (i & 1) ? v.w : v.z;
    return (i & 2) ? cd : ab;
}
__device__ __forceinline__ float lrelu(float t) { return (t > 0.f) ? t : 0.2f * t; }

// ---------------- GAT agg, layer 1 (H=4, 256 ch, bf16 payload) ----------------

__global__ __launch_bounds__(256) void gat_agg_h4b_k(
    const unsigned short* __restrict__ hb, const float* __restrict__ al_s,
    const float* __restrict__ al_d, const int* __restrict__ offs,
    const int* __restrict__ csr_src, const float* __restrict__ bias,
    float* __restrict__ out, int N)
{
    __shared__ float4 alds[4][64];
    __shared__ int    slds[4][64];
    int w = threadIdx.x >> 6, lane = threadIdx.x & 63;
    int node = blockIdx.x * 4 + w;
    if (node >= N) return;
    int hd = lane >> 4;
    int beg = offs[node], end = offs[node + 1];
    float4 ald4 = *(const float4*)&al_d[(size_t)node * 4];
    float4 m4 = make_float4(-1e30f, -1e30f, -1e30f, -1e30f);
    float4 z4 = make_float4(0.f, 0.f, 0.f, 0.f);
    float4 acc = make_float4(0.f, 0.f, 0.f, 0.f);

    for (int base = beg; base < end; base += 64) {
        int cnt = min(64, end - base);
        int s = 0;
        float4 l4 = make_float4(-1e30f, -1e30f, -1e30f, -1e30f);
        if (lane < cnt) {
            s = csr_src[base + lane];
            float4 as4 = *(const float4*)&al_s[(size_t)s * 4];
            l4.x = lrelu(as4.x + ald4.x);
            l4.y = lrelu(as4.y + ald4.y);
            l4.z = lrelu(as4.z + ald4.z);
            l4.w = lrelu(as4.w + ald4.w);
        }
        float4 mc = l4;
        #pragma unroll
        for (int d = 32; d; d >>= 1) mc = max4(mc, shflx4(mc, d));
        float4 mn = max4(m4, mc);
        float4 p4;
        p4.x = __expf(l4.x - mn.x);
        p4.y = __expf(l4.y - mn.y);
        p4.z = __expf(l4.z - mn.z);
        p4.w = __expf(l4.w - mn.w);
        float4 zc = p4;
        #pragma unroll
        for (int d = 32; d; d >>= 1) {
            float4 t = shflx4(zc, d);
            zc.x += t.x; zc.y += t.y; zc.z += t.z; zc.w += t.w;
        }
        float4 sc;
        sc.x = __expf(m4.x - mn.x); sc.y = __expf(m4.y - mn.y);
        sc.z = __expf(m4.z - mn.z); sc.w = __expf(m4.w - mn.w);
        z4.x = z4.x * sc.x + zc.x; z4.y = z4.y * sc.y + zc.y;
        z4.z = z4.z * sc.z + zc.z; z4.w = z4.w * sc.w + zc.w;
        float asc = sel4(sc, hd);
        acc.x *= asc; acc.y *= asc; acc.z *= asc; acc.w *= asc;
        alds[w][lane] = p4;
        slds[w][lane] = s;
        #pragma unroll 4
        for (int e = 0; e < cnt; ++e) {
            float a = sel4(alds[w][e], hd);
            int ss = slds[w][e];
            ushort4 hv = *(const ushort4*)&hb[(size_t)ss * 256 + lane * 4];
            acc.x += a * bf2f(hv.x); acc.y += a * bf2f(hv.y);
            acc.z += a * bf2f(hv.z); acc.w += a * bf2f(hv.w);
        }
        m4 = mn;
    }

    float rz = 1.f / sel4(z4, hd);
    float4 b4 = *(const float4*)&bias[lane * 4];
    float4 v;
    v.x = fmaxf(acc.x * rz + b4.x, 0.f);
    v.y = fmaxf(acc.y * rz + b4.y, 0.f);
    v.z = fmaxf(acc.z * rz + b4.z, 0.f);
    v.w = fmaxf(acc.w * rz + b4.w, 0.f);
    *(float4*)&out[(size_t)node * 256 + lane * 4] = v;
}

// ---------------- GAT agg, layer 2 (H=1, 64 ch, f32) ----------------

__global__ __launch_bounds__(256) void gat_agg_h1_k(
    const float* __restrict__ h, const float* __restrict__ al_s,
    const float* __restrict__ al_d, const int* __restrict__ offs,
    const int* __restrict__ csr_src, const float* __restrict__ bias,
    float* __restrict__ out, int N)
{
    __shared__ float alds[4][64];
    __shared__ int   slds[4][64];
    int w = threadIdx.x >> 6, lane = threadIdx.x & 63;
    int node = blockIdx.x * 4 + w;
    if (node >= N) return;
    int es = lane >> 4, c4 = lane & 15;
    int beg = offs[node], end = offs[node + 1];
    float ald = al_d[node];
    float m_run = -1e30f, z_run = 0.f;
    float4 acc = make_float4(0.f, 0.f, 0.f, 0.f);

    for (int base = beg; base < end; base += 64) {
        int cnt = min(64, end - base);
        int s = 0; float l = -1e30f;
        if (lane < cnt) {
            s = csr_src[base + lane];
            l = lrelu(al_s[s] + ald);
        }
        float mc = l;
        #pragma unroll
        for (int d = 32; d; d >>= 1) mc = fmaxf(mc, __shfl_xor(mc, d, 64));
        float mn = fmaxf(m_run, mc);
        float p = __expf(l - mn);
        float zc = p;
        #pragma unroll
        for (int d = 32; d; d >>= 1) zc += __shfl_xor(zc, d, 64);
        float sc = __expf(m_run - mn);
        z_run = z_run * sc + zc;
        acc.x *= sc; acc.y *= sc; acc.z *= sc; acc.w *= sc;
        alds[w][lane] = p;
        slds[w][lane] = s;
        for (int eb = 0; eb < cnt; eb += 4) {
            int e = eb + es;
            float a = alds[w][e];
            int ss = slds[w][e];
            float4 hv = *(const float4*)&h[(size_t)ss * 64 + c4 * 4];
            acc.x += a * hv.x; acc.y += a * hv.y;
            acc.z += a * hv.z; acc.w += a * hv.w;
        }
        m_run = mn;
    }

    {
        float4 t = shflx4(acc, 16);
        acc.x += t.x; acc.y += t.y; acc.z += t.z; acc.w += t.w;
        t = shflx4(acc, 32);
        acc.x += t.x; acc.y += t.y; acc.z += t.z; acc.w += t.w;
    }
    if (es == 0) {
        float rz = 1.f / z_run;
        float4 b4 = *(const float4*)&bias[c4 * 4];
        float4 v;
        v.x = acc.x * rz + b4.x;
        v.y = acc.y * rz + b4.y;
        v.z = acc.z * rz + b4.z;
        v.w = acc.w * rz + b4.w;
        *(float4*)&out[(size_t)node * 64 + c4 * 4] = v;
    }
}

// ---------------- launch ----------------

extern "C" void kernel_launch(void* const* d_in, const int* in_sizes, int n_in,
                              void* d_out, int out_size, void* d_ws, size_t ws_size,
                              hipStream_t stream) {
    const float* x   = (const float*)d_in[0];
    const int*   ei  = (const int*)d_in[1];
    const float* W1  = (const float*)d_in[2];
    const float* as1 = (const float*)d_in[3];
    const float* ad1 = (const float*)d_in[4];
    const float* b1  = (const float*)d_in[5];
    const float* W2  = (const float*)d_in[6];
    const float* as2 = (const float*)d_in[7];
    const float* ad2 = (const float*)d_in[8];
    const float* b2  = (const float*)d_in[9];
    const float* Wf  = (const float*)d_in[10];
    const float* bf  = (const float*)d_in[11];
    float* out = (float*)d_out;

    int N = in_sizes[0] / 256;   // 50000
    int E = in_sizes[1] / 2;     // 800000
    int ET = E + N;

    char* w = (char*)d_ws;
    float* big  = (float*)w;                                  // N*256 f32 region
    float* out1 = (float*)(w + (size_t)N * 256 * 4);          // N*256 f32
    char*  p    = w + (size_t)N * 256 * 4 * 2;
    unsigned short* h1b = (unsigned short*)p;  p += (size_t)N * 256 * 2;   // bf16 h1
    float* al_s1 = (float*)p;            p += (size_t)N * 4 * 4;
    float* al_d1 = (float*)p;            p += (size_t)N * 4 * 4;
    float* al_s2 = (float*)p;            p += (size_t)N * 4;
    float* al_d2 = (float*)p;            p += (size_t)N * 4;
    int* counts  = (int*)p;              p += (size_t)N * 4;
    int* offs    = (int*)p;              p += (size_t)(N + 1) * 4;
    int* cursor  = (int*)p;              p += (size_t)N * 4;
    int* csr_src = (int*)p;              p += (size_t)ET * 4;
    unsigned short* W1bT = (unsigned short*)p;  p += (size_t)256 * 256 * 2;
    // overlays in `big` (lifetimes disjoint):
    unsigned short* xb = (unsigned short*)big;   // N*256 bf16, dead after GEMM1
    float* h2   = big;                            // N*64 f32 (layer 2)
    float* out2 = big + (size_t)N * 64;           // N*64 f32

    // CSR build
    hipMemsetAsync(counts, 0, (size_t)N * sizeof(int), stream);
    count_edges_k<<<(ET + 255) / 256, 256, 0, stream>>>(ei, counts, E, N);
    scan_k<<<1, 1024, 0, stream>>>(counts, offs, cursor, N);
    fill_csr_k<<<(ET + 255) / 256, 256, 0, stream>>>(ei, cursor, csr_src, E, N);

    // converts for MFMA GEMM1
    {
        int n4 = N * 256 / 4;
        f2bf4_k<<<(n4 + 255) / 256, 256, 0, stream>>>(x, xb, n4);
        w1t_k<<<256, 256, 0, stream>>>(W1, W1bT);
    }

    // layer 1: h1b = bf16(xb @ W1) via MFMA
    {
        dim3 g((N + 127) / 128, 2);
        gemm_mfma1_k<<<g, 256, 0, stream>>>(xb, W1bT, h1b, N);
    }
    att_b_k<<<N, 256, 0, stream>>>(h1b, as1, ad1, al_s1, al_d1, 4, 64);
    gat_agg_h4b_k<<<(N + 3) / 4, 256, 0, stream>>>(h1b, al_s1, al_d1, offs, csr_src, b1, out1, N);

    // layer 2 (f32, 64x64 tiles for occupancy)
    {
        dim3 g((N + 63) / 64, 1);
        gemm2_k<64, 64, 4, 4, false><<<g, 256, 0, stream>>>(out1, W2, nullptr, h2, nullptr, N, 256, 64, 0);
    }
    att_k<<<N, 64, 0, stream>>>(h2, as2, ad2, al_s2, al_d2, 1, 64);
    gat_agg_h1_k<<<(N + 3) / 4, 256, 0, stream>>>(h2, al_s2, al_d2, offs, csr_src, b2, out2, N);

    // final linear (f32)
    {
        dim3 g((N + 127) / 128, 256 / 128);
        gemm2_k<128, 128, 8, 8, false><<<g, 256, 0, stream>>>(out2, Wf, bf, out, nullptr, N, 64, 256, 0);
    }
}

// Round 7
// 343.743 us; speedup vs baseline: 2.6728x; 1.1906x over previous
//
#include <hip/hip_runtime.h>
#include <cstddef>
#include <cstdint>

// ---------------- bf16 helpers ----------------

__device__ __forceinline__ unsigned short f2bf(float f) {
    uint32_t u = __float_as_uint(f);
    u += 0x7FFFu + ((u >> 16) & 1u);
    return (unsigned short)(u >> 16);
}
__device__ __forceinline__ float bf2f(unsigned short b) {
    return __uint_as_float(((uint32_t)b) << 16);
}

typedef __attribute__((ext_vector_type(8))) short bf16x8;
typedef __attribute__((ext_vector_type(4))) float f32x4;

// ---------------- CSR construction ----------------

__global__ void count_edges_k(const int* __restrict__ ei, int* __restrict__ counts,
                              int E, int N) {
    int e = blockIdx.x * blockDim.x + threadIdx.x;
    int tot = E + N;
    if (e >= tot) return;
    int d = (e < E) ? ei[E + e] : (e - E);
    atomicAdd(&counts[d], 1);
}

// 4 elements/thread single-block scan: 13 iterations for N=50000.
__global__ __launch_bounds__(1024) void scan4_k(const int* __restrict__ counts,
                                                int* __restrict__ offs,
                                                int* __restrict__ cursor, int N) {
    __shared__ int wsum[16];
    __shared__ int carry_s;
    int tid = threadIdx.x, lane = tid & 63, w = tid >> 6;
    if (tid == 0) { carry_s = 0; offs[0] = 0; }
    __syncthreads();
    for (int base = 0; base < N; base += 4096) {
        int i0 = base + tid * 4;
        int v0 = 0, v1 = 0, v2 = 0, v3 = 0;
        if (i0 + 3 < N) {
            int4 v = *(const int4*)&counts[i0];
            v0 = v.x; v1 = v.y; v2 = v.z; v3 = v.w;
        } else {
            if (i0 + 0 < N) v0 = counts[i0 + 0];
            if (i0 + 1 < N) v1 = counts[i0 + 1];
            if (i0 + 2 < N) v2 = counts[i0 + 2];
        }
        int s0 = v0, s1 = s0 + v1, s2 = s1 + v2, s3 = s2 + v3;
        int x = s3;
        #pragma unroll
        for (int d = 1; d < 64; d <<= 1) {
            int t = __shfl_up(x, d, 64);
            if (lane >= d) x += t;
        }
        if (lane == 63) wsum[w] = x;
        __syncthreads();
        if (tid == 0) {
            int run = 0;
            for (int k = 0; k < 16; k++) { run += wsum[k]; wsum[k] = run; }
        }
        __syncthreads();
        int excl = (x - s3) + (w > 0 ? wsum[w - 1] : 0) + carry_s;
        if (i0 + 0 < N) { cursor[i0 + 0] = excl;      offs[i0 + 1] = excl + s0; }
        if (i0 + 1 < N) { cursor[i0 + 1] = excl + s0; offs[i0 + 2] = excl + s1; }
        if (i0 + 2 < N) { cursor[i0 + 2] = excl + s1; offs[i0 + 3] = excl + s2; }
        if (i0 + 3 < N) { cursor[i0 + 3] = excl + s2; offs[i0 + 4] = excl + s3; }
        __syncthreads();
        if (tid == 0) carry_s += wsum[15];
        __syncthreads();
    }
}

__global__ void fill_csr_k(const int* __restrict__ ei, int* __restrict__ cursor,
                           int* __restrict__ csr_src, int E, int N) {
    int e = blockIdx.x * blockDim.x + threadIdx.x;
    int tot = E + N;
    if (e >= tot) return;
    int s, d;
    if (e < E) { s = ei[e]; d = ei[E + e]; }
    else       { s = e - E; d = s; }
    int pos = atomicAdd(&cursor[d], 1);
    csr_src[pos] = s;
}

// ---------------- converts ----------------

__global__ void f2bf4_k(const float* __restrict__ in, unsigned short* __restrict__ out, int n4) {
    int i = blockIdx.x * blockDim.x + threadIdx.x;
    if (i >= n4) return;
    float4 v = ((const float4*)in)[i];
    ushort4 o;
    o.x = f2bf(v.x); o.y = f2bf(v.y); o.z = f2bf(v.z); o.w = f2bf(v.w);
    ((ushort4*)out)[i] = o;
}

// W [K][Nc] f32 -> WT [Nc][K] bf16
__global__ void wt_k(const float* __restrict__ W, unsigned short* __restrict__ WT,
                     int K, int Nc) {
    int n = blockIdx.x;
    for (int k = threadIdx.x; k < K; k += blockDim.x)
        WT[(size_t)n * K + k] = f2bf(W[(size_t)k * Nc + n]);
}

// ---------------- generalized MFMA bf16 GEMM ----------------
// C[M,Nc] = A[M,KD] @ BT[Nc,KD]^T, 128xBN tile, 4 waves (2x2), BK=32.
// LDS [row][kk] with stride 40 bf16 (80B = 5*16B: b128-aligned, uniform banks).
// OUTB: bf16 out (RNE); else f32 out (+bias if HASBIAS).

template<int KD, int BN, int NI, bool OUTB, bool HASBIAS>
__global__ __launch_bounds__(256) void gemm_mfma_k(
    const unsigned short* __restrict__ Ab,
    const unsigned short* __restrict__ BT,
    const float* __restrict__ bias,
    unsigned short* __restrict__ Cb,
    float* __restrict__ Cf,
    int M, int Nc)
{
    const int SA = 40;
    __shared__ unsigned short As[128 * SA];
    __shared__ unsigned short Bs[BN * SA];
    int tid = threadIdx.x;
    int lane = tid & 63, wid = tid >> 6;
    int wm = wid >> 1, wn = wid & 1;
    int bm = blockIdx.x * 128, bn = blockIdx.y * BN;

    f32x4 acc[4][NI];
    #pragma unroll
    for (int mi = 0; mi < 4; ++mi)
        #pragma unroll
        for (int ni = 0; ni < NI; ++ni) {
            acc[mi][ni][0] = 0.f; acc[mi][ni][1] = 0.f;
            acc[mi][ni][2] = 0.f; acc[mi][ni][3] = 0.f;
        }

    int srow = tid >> 2;   // 0..63
    int skc  = tid & 3;    // 8-bf16 chunk within BK=32

    for (int k0 = 0; k0 < KD; k0 += 32) {
        #pragma unroll
        for (int q = 0; q < 2; ++q) {
            int row = q * 64 + srow;
            int4 av = make_int4(0, 0, 0, 0);
            int gr = bm + row;
            if (gr < M) av = *(const int4*)&Ab[(size_t)gr * KD + k0 + skc * 8];
            *(int4*)&As[row * SA + skc * 8] = av;
        }
        #pragma unroll
        for (int q = 0; q < BN / 64; ++q) {
            int row = q * 64 + srow;
            int4 bv = *(const int4*)&BT[(size_t)(bn + row) * KD + k0 + skc * 8];
            *(int4*)&Bs[row * SA + skc * 8] = bv;
        }
        __syncthreads();

        bf16x8 af[4], bfv[NI];
        #pragma unroll
        for (int mi = 0; mi < 4; ++mi)
            af[mi] = *(const bf16x8*)&As[(wm * 64 + mi * 16 + (lane & 15)) * SA + (lane >> 4) * 8];
        #pragma unroll
        for (int ni = 0; ni < NI; ++ni)
            bfv[ni] = *(const bf16x8*)&Bs[(wn * (NI * 16) + ni * 16 + (lane & 15)) * SA + (lane >> 4) * 8];
        #pragma unroll
        for (int mi = 0; mi < 4; ++mi)
            #pragma unroll
            for (int ni = 0; ni < NI; ++ni)
                acc[mi][ni] = __builtin_amdgcn_mfma_f32_16x16x32_bf16(af[mi], bfv[ni], acc[mi][ni], 0, 0, 0);
        __syncthreads();
    }

    // D: col = lane&15 (+16*ni), row = (lane>>4)*4 + reg
    #pragma unroll
    for (int mi = 0; mi < 4; ++mi) {
        #pragma unroll
        for (int j = 0; j < 4; ++j) {
            int row = bm + wm * 64 + mi * 16 + (lane >> 4) * 4 + j;
            if (row >= M) continue;
            #pragma unroll
            for (int ni = 0; ni < NI; ++ni) {
                int col = bn + wn * (NI * 16) + ni * 16 + (lane & 15);
                if (OUTB) {
                    Cb[(size_t)row * Nc + col] = f2bf(acc[mi][ni][j]);
                } else {
                    float v = acc[mi][ni][j] + (HASBIAS ? bias[col] : 0.f);
                    Cf[(size_t)row * Nc + col] = v;
                }
            }
        }
    }
}

// ---------------- per-node attention logits (bf16 input) ----------------

__global__ void att_b_k(const unsigned short* __restrict__ hb, const float* __restrict__ as_,
                        const float* __restrict__ ad_, float* __restrict__ al_s,
                        float* __restrict__ al_d, int H, int C) {
    int n = blockIdx.x;
    int t = threadIdx.x;
    int hd = t / C;
    int c = t % C;
    float hv = bf2f(hb[(size_t)n * H * C + t]);
    float ps = hv * as_[t];
    float pd = hv * ad_[t];
    #pragma unroll
    for (int d = 32; d > 0; d >>= 1) {
        ps += __shfl_down(ps, d, 64);
        pd += __shfl_down(pd, d, 64);
    }
    if (c == 0) {
        al_s[(size_t)n * H + hd] = ps;
        al_d[(size_t)n * H + hd] = pd;
    }
}

// ---------------- float4 helpers ----------------

__device__ __forceinline__ float4 shflx4(float4 v, int d) {
    float4 r;
    r.x = __shfl_xor(v.x, d, 64);
    r.y = __shfl_xor(v.y, d, 64);
    r.z = __shfl_xor(v.z, d, 64);
    r.w = __shfl_xor(v.w, d, 64);
    return r;
}
__device__ __forceinline__ float4 max4(float4 a, float4 b) {
    return make_float4(fmaxf(a.x, b.x), fmaxf(a.y, b.y), fmaxf(a.z, b.z), fmaxf(a.w, b.w));
}
__device__ __forceinline__ float sel4(float4 v, int i) {
    float ab = (i & 1) ? v.y : v.x;
    float cd = (i & 1) ? v.w : v.z;
    return (i & 2) ? cd : ab;
}
__device__ __forceinline__ float lrelu(float t) { return (t > 0.f) ? t : 0.2f * t; }

// ---------------- GAT agg, layer 1 (H=4, 256 ch, bf16 in, bf16 out) ----------------

__global__ __launch_bounds__(256) void gat_agg_h4b_k(
    const unsigned short* __restrict__ hb, const float* __restrict__ al_s,
    const float* __restrict__ al_d, const int* __restrict__ offs,
    const int* __restrict__ csr_src, const float* __restrict__ bias,
    unsigned short* __restrict__ outb, int N)
{
    __shared__ float4 alds[4][64];
    __shared__ int    slds[4][64];
    int w = threadIdx.x >> 6, lane = threadIdx.x & 63;
    int node = blockIdx.x * 4 + w;
    if (node >= N) return;
    int hd = lane >> 4;
    int beg = offs[node], end = offs[node + 1];
    float4 ald4 = *(const float4*)&al_d[(size_t)node * 4];
    float4 m4 = make_float4(-1e30f, -1e30f, -1e30f, -1e30f);
    float4 z4 = make_float4(0.f, 0.f, 0.f, 0.f);
    float4 acc = make_float4(0.f, 0.f, 0.f, 0.f);

    for (int base = beg; base < end; base += 64) {
        int cnt = min(64, end - base);
        int s = 0;
        float4 l4 = make_float4(-1e30f, -1e30f, -1e30f, -1e30f);
        if (lane < cnt) {
            s = csr_src[base + lane];
            float4 as4 = *(const float4*)&al_s[(size_t)s * 4];
            l4.x = lrelu(as4.x + ald4.x);
            l4.y = lrelu(as4.y + ald4.y);
            l4.z = lrelu(as4.z + ald4.z);
            l4.w = lrelu(as4.w + ald4.w);
        }
        float4 mc = l4;
        #pragma unroll
        for (int d = 32; d; d >>= 1) mc = max4(mc, shflx4(mc, d));
        float4 mn = max4(m4, mc);
        float4 p4;
        p4.x = __expf(l4.x - mn.x);
        p4.y = __expf(l4.y - mn.y);
        p4.z = __expf(l4.z - mn.z);
        p4.w = __expf(l4.w - mn.w);
        float4 zc = p4;
        #pragma unroll
        for (int d = 32; d; d >>= 1) {
            float4 t = shflx4(zc, d);
            zc.x += t.x; zc.y += t.y; zc.z += t.z; zc.w += t.w;
        }
        float4 sc;
        sc.x = __expf(m4.x - mn.x); sc.y = __expf(m4.y - mn.y);
        sc.z = __expf(m4.z - mn.z); sc.w = __expf(m4.w - mn.w);
        z4.x = z4.x * sc.x + zc.x; z4.y = z4.y * sc.y + zc.y;
        z4.z = z4.z * sc.z + zc.z; z4.w = z4.w * sc.w + zc.w;
        float asc = sel4(sc, hd);
        acc.x *= asc; acc.y *= asc; acc.z *= asc; acc.w *= asc;
        alds[w][lane] = p4;
        slds[w][lane] = s;
        #pragma unroll 4
        for (int e = 0; e < cnt; ++e) {
            float a = sel4(alds[w][e], hd);
            int ss = slds[w][e];
            ushort4 hv = *(const ushort4*)&hb[(size_t)ss * 256 + lane * 4];
            acc.x += a * bf2f(hv.x); acc.y += a * bf2f(hv.y);
            acc.z += a * bf2f(hv.z); acc.w += a * bf2f(hv.w);
        }
        m4 = mn;
    }

    float rz = 1.f / sel4(z4, hd);
    float4 b4 = *(const float4*)&bias[lane * 4];
    ushort4 o;
    o.x = f2bf(fmaxf(acc.x * rz + b4.x, 0.f));
    o.y = f2bf(fmaxf(acc.y * rz + b4.y, 0.f));
    o.z = f2bf(fmaxf(acc.z * rz + b4.z, 0.f));
    o.w = f2bf(fmaxf(acc.w * rz + b4.w, 0.f));
    *(ushort4*)&outb[(size_t)node * 256 + lane * 4] = o;
}

// ---------------- GAT agg, layer 2 (H=1, 64 ch, bf16 in, bf16 out) ----------------
// lane = es*16 + c4: 16 lanes x ushort4 cover the 128B row; 4 edge-subslots parallel.

__global__ __launch_bounds__(256) void gat_agg_h1b_k(
    const unsigned short* __restrict__ hb, const float* __restrict__ al_s,
    const float* __restrict__ al_d, const int* __restrict__ offs,
    const int* __restrict__ csr_src, const float* __restrict__ bias,
    unsigned short* __restrict__ outb, int N)
{
    __shared__ float alds[4][64];
    __shared__ int   slds[4][64];
    int w = threadIdx.x >> 6, lane = threadIdx.x & 63;
    int node = blockIdx.x * 4 + w;
    if (node >= N) return;
    int es = lane >> 4, c4 = lane & 15;
    int beg = offs[node], end = offs[node + 1];
    float ald = al_d[node];
    float m_run = -1e30f, z_run = 0.f;
    float4 acc = make_float4(0.f, 0.f, 0.f, 0.f);

    for (int base = beg; base < end; base += 64) {
        int cnt = min(64, end - base);
        int s = 0; float l = -1e30f;
        if (lane < cnt) {
            s = csr_src[base + lane];
            l = lrelu(al_s[s] + ald);
        }
        float mc = l;
        #pragma unroll
        for (int d = 32; d; d >>= 1) mc = fmaxf(mc, __shfl_xor(mc, d, 64));
        float mn = fmaxf(m_run, mc);
        float p = __expf(l - mn);
        float zc = p;
        #pragma unroll
        for (int d = 32; d; d >>= 1) zc += __shfl_xor(zc, d, 64);
        float sc = __expf(m_run - mn);
        z_run = z_run * sc + zc;
        acc.x *= sc; acc.y *= sc; acc.z *= sc; acc.w *= sc;
        alds[w][lane] = p;
        slds[w][lane] = s;
        for (int eb = 0; eb < cnt; eb += 4) {
            int e = eb + es;
            float a = alds[w][e];
            int ss = slds[w][e];
            ushort4 hv = *(const ushort4*)&hb[(size_t)ss * 64 + c4 * 4];
            acc.x += a * bf2f(hv.x); acc.y += a * bf2f(hv.y);
            acc.z += a * bf2f(hv.z); acc.w += a * bf2f(hv.w);
        }
        m_run = mn;
    }

    {
        float4 t = shflx4(acc, 16);
        acc.x += t.x; acc.y += t.y; acc.z += t.z; acc.w += t.w;
        t = shflx4(acc, 32);
        acc.x += t.x; acc.y += t.y; acc.z += t.z; acc.w += t.w;
    }
    if (es == 0) {
        float rz = 1.f / z_run;
        float4 b4 = *(const float4*)&bias[c4 * 4];
        ushort4 o;
        o.x = f2bf(acc.x * rz + b4.x);
        o.y = f2bf(acc.y * rz + b4.y);
        o.z = f2bf(acc.z * rz + b4.z);
        o.w = f2bf(acc.w * rz + b4.w);
        *(ushort4*)&outb[(size_t)node * 64 + c4 * 4] = o;
    }
}

// ---------------- launch ----------------

extern "C" void kernel_launch(void* const* d_in, const int* in_sizes, int n_in,
                              void* d_out, int out_size, void* d_ws, size_t ws_size,
                              hipStream_t stream) {
    const float* x   = (const float*)d_in[0];
    const int*   ei  = (const int*)d_in[1];
    const float* W1  = (const float*)d_in[2];
    const float* as1 = (const float*)d_in[3];
    const float* ad1 = (const float*)d_in[4];
    const float* b1  = (const float*)d_in[5];
    const float* W2  = (const float*)d_in[6];
    const float* as2 = (const float*)d_in[7];
    const float* ad2 = (const float*)d_in[8];
    const float* b2  = (const float*)d_in[9];
    const float* Wf  = (const float*)d_in[10];
    const float* bf  = (const float*)d_in[11];
    float* out = (float*)d_out;

    int N = in_sizes[0] / 256;   // 50000
    int E = in_sizes[1] / 2;     // 800000
    int ET = E + N;

    char* w = (char*)d_ws;
    float* big   = (float*)w;                                 // N*256 f32 region (overlays)
    unsigned short* out1b = (unsigned short*)(w + (size_t)N * 256 * 4);  // N*256 bf16
    char*  p     = w + (size_t)N * 256 * 4 * 2;
    unsigned short* h1b = (unsigned short*)p;  p += (size_t)N * 256 * 2;
    float* al_s1 = (float*)p;            p += (size_t)N * 4 * 4;
    float* al_d1 = (float*)p;            p += (size_t)N * 4 * 4;
    float* al_s2 = (float*)p;            p += (size_t)N * 4;
    float* al_d2 = (float*)p;            p += (size_t)N * 4;
    int* counts  = (int*)p;              p += (size_t)N * 4;
    int* offs    = (int*)p;              p += (size_t)(N + 1) * 4 + 12;  // keep 16B alignment
    int* cursor  = (int*)p;              p += (size_t)N * 4;
    int* csr_src = (int*)p;              p += (size_t)ET * 4;
    unsigned short* W1bT = (unsigned short*)p;  p += (size_t)256 * 256 * 2;
    unsigned short* W2bT = (unsigned short*)p;  p += (size_t)64 * 256 * 2;
    unsigned short* WfbT = (unsigned short*)p;  p += (size_t)256 * 64 * 2;
    // overlays in `big` (lifetimes disjoint):
    unsigned short* xb    = (unsigned short*)big;                  // N*256 bf16, dead after GEMM1
    unsigned short* h2b   = (unsigned short*)big;                  // N*64 bf16 (layer 2)
    unsigned short* out2b = (unsigned short*)big + (size_t)N * 64; // N*64 bf16

    // CSR build
    hipMemsetAsync(counts, 0, (size_t)N * sizeof(int), stream);
    count_edges_k<<<(ET + 255) / 256, 256, 0, stream>>>(ei, counts, E, N);
    scan4_k<<<1, 1024, 0, stream>>>(counts, offs, cursor, N);
    fill_csr_k<<<(ET + 255) / 256, 256, 0, stream>>>(ei, cursor, csr_src, E, N);

    // converts
    {
        int n4 = N * 256 / 4;
        f2bf4_k<<<(n4 + 255) / 256, 256, 0, stream>>>(x, xb, n4);
        wt_k<<<256, 256, 0, stream>>>(W1, W1bT, 256, 256);
        wt_k<<<64, 256, 0, stream>>>(W2, W2bT, 256, 64);
        wt_k<<<256, 64, 0, stream>>>(Wf, WfbT, 64, 256);
    }

    // layer 1: h1b = bf16(xb @ W1)
    {
        dim3 g((N + 127) / 128, 2);
        gemm_mfma_k<256, 128, 4, true, false><<<g, 256, 0, stream>>>(xb, W1bT, nullptr, h1b, nullptr, N, 256);
    }
    att_b_k<<<N, 256, 0, stream>>>(h1b, as1, ad1, al_s1, al_d1, 4, 64);
    gat_agg_h4b_k<<<(N + 3) / 4, 256, 0, stream>>>(h1b, al_s1, al_d1, offs, csr_src, b1, out1b, N);

    // layer 2: h2b = bf16(out1b @ W2)
    {
        dim3 g((N + 127) / 128, 1);
        gemm_mfma_k<256, 64, 2, true, false><<<g, 256, 0, stream>>>(out1b, W2bT, nullptr, h2b, nullptr, N, 64);
    }
    att_b_k<<<N, 64, 0, stream>>>(h2b, as2, ad2, al_s2, al_d2, 1, 64);
    gat_agg_h1b_k<<<(N + 3) / 4, 256, 0, stream>>>(h2b, al_s2, al_d2, offs, csr_src, b2, out2b, N);

    // final: out = out2b @ Wf + bf (f32 out)
    {
        dim3 g((N + 127) / 128, 2);
        gemm_mfma_k<64, 128, 4, false, true><<<g, 256, 0, stream>>>(out2b, WfbT, bf, nullptr, out, N, 256);
    }
}